// Round 3
// baseline (231.130 us; speedup 1.0000x reference)
//
#include <hip/hip_runtime.h>

typedef __bf16 bf16x8 __attribute__((ext_vector_type(8)));
typedef __bf16 bf16x4 __attribute__((ext_vector_type(4)));
typedef float  f32x4  __attribute__((ext_vector_type(4)));
typedef float  f32x16 __attribute__((ext_vector_type(16)));
typedef unsigned u32x2 __attribute__((ext_vector_type(2)));

#define DEVINL __device__ __forceinline__

DEVINL void gload_lds16(const void* g, void* l) {
  __builtin_amdgcn_global_load_lds((const __attribute__((address_space(1))) void*)g,
                                   (__attribute__((address_space(3))) void*)l, 16, 0, 0);
}

DEVINL unsigned pkbf(float a, float b) {
  union { __bf16 h[2]; unsigned u; } c;
  c.h[0] = (__bf16)a; c.h[1] = (__bf16)b;
  return c.u;
}

// exchange lane halves: returns {x from lanes0-31 view, x from lanes32-63 view}
DEVINL float2 swap32(float x) {
  u32x2 r = __builtin_amdgcn_permlane32_swap(__float_as_uint(x), __float_as_uint(x), false, false);
  return make_float2(__uint_as_float(r.x), __uint_as_float(r.y));
}

// ---------------- RMSNorm over hidden=1024 + cast to bf16 (two tensors, one launch) ----------------
__global__ __launch_bounds__(256) void rmsnorm2_kernel(
    const float* __restrict__ XA, const float* __restrict__ WA, __bf16* __restrict__ YA, int nA,
    const float* __restrict__ XB, const float* __restrict__ WB, __bf16* __restrict__ YB) {
  int rb = blockIdx.x, tid = threadIdx.x;
  const float* X; const float* W; __bf16* Y; int row;
  if (rb < nA) { X = XA; W = WA; Y = YA; row = rb; }
  else { X = XB; W = WB; Y = YB; row = rb - nA; }
  const float4* xr = (const float4*)(X + (size_t)row * 1024);
  float4 v = xr[tid];
  float ss = v.x * v.x + v.y * v.y + v.z * v.z + v.w * v.w;
#pragma unroll
  for (int m = 1; m < 64; m <<= 1) ss += __shfl_xor(ss, m);
  __shared__ float part[4];
  if ((tid & 63) == 0) part[tid >> 6] = ss;
  __syncthreads();
  float tot = part[0] + part[1] + part[2] + part[3];
  float rn = rsqrtf(tot * (1.0f / 1024.0f) + 1e-6f);
  float4 wv = ((const float4*)W)[tid];
  bf16x4 y;
  y[0] = (__bf16)(v.x * rn * wv.x);
  y[1] = (__bf16)(v.y * rn * wv.y);
  y[2] = (__bf16)(v.z * rn * wv.z);
  y[3] = (__bf16)(v.w * rn * wv.w);
  *(bf16x4*)(Y + (size_t)row * 1024 + tid * 4) = y;
}

// ---------------- cast 4 weight matrices (1024x1024 each) to bf16 ----------------
__global__ __launch_bounds__(256) void cast_w_kernel(
    const float* __restrict__ a, const float* __restrict__ b,
    const float* __restrict__ c, const float* __restrict__ d,
    __bf16* __restrict__ oa, __bf16* __restrict__ ob,
    __bf16* __restrict__ oc, __bf16* __restrict__ od) {
  int gid = blockIdx.x * 256 + threadIdx.x;
  int which = gid >> 17;
  size_t off = (size_t)(gid & 131071) * 8;
  const float* s = (which == 0) ? a : (which == 1) ? b : (which == 2) ? c : d;
  __bf16* o = (which == 0) ? oa : (which == 1) ? ob : (which == 2) ? oc : od;
  float4 v0 = *(const float4*)(s + off), v1 = *(const float4*)(s + off + 4);
  bf16x8 y;
  y[0] = (__bf16)v0.x; y[1] = (__bf16)v0.y; y[2] = (__bf16)v0.z; y[3] = (__bf16)v0.w;
  y[4] = (__bf16)v1.x; y[5] = (__bf16)v1.y; y[6] = (__bf16)v1.z; y[7] = (__bf16)v1.w;
  *(bf16x8*)(o + off) = y;
}

// ---------------- 128x128 tile bf16 GEMM, C = A @ W^T + bias (B^T layout) ----------------
// EPI=0: bf16 out. EPI=1: f32 out = resid + alpha*(acc+bias). EPI=2: merged dual-output
// (grid.y=16 over 2048 weight rows; n0>=1024 -> bias2/Cout2).
template <int EPI>
__global__ __launch_bounds__(256) void gemm_bt_kernel(
    const __bf16* __restrict__ A, const __bf16* __restrict__ Bw,
    const float* __restrict__ bias, void* __restrict__ Cout,
    const float* __restrict__ resid, const float* __restrict__ alphap,
    const float* __restrict__ bias2, void* __restrict__ Cout2) {
  __shared__ __attribute__((aligned(16))) __bf16 As[128 * 32];
  __shared__ __attribute__((aligned(16))) __bf16 Bs[128 * 32];
  int tid = threadIdx.x, lane = tid & 63, w = tid >> 6, wr = w >> 1, wc = w & 1;
  int m0 = blockIdx.x * 128, n0 = blockIdx.y * 128;
  f32x4 z4 = {0.f, 0.f, 0.f, 0.f};
  f32x4 acc[4][4];
#pragma unroll
  for (int i = 0; i < 4; i++)
#pragma unroll
    for (int j = 0; j < 4; j++) acc[i][j] = z4;

  for (int k0 = 0; k0 < 1024; k0 += 32) {
#pragma unroll
    for (int i = 0; i < 2; i++) {
      int chunk = i * 256 + tid;
      int row = chunk >> 2, cc = chunk & 3;
      gload_lds16(A + (size_t)(m0 + row) * 1024 + k0 + cc * 8, (char*)As + i * 4096 + w * 1024);
      gload_lds16(Bw + (size_t)(n0 + row) * 1024 + k0 + cc * 8, (char*)Bs + i * 4096 + w * 1024);
    }
    __syncthreads();
    bf16x8 af[4], bfr[4];
#pragma unroll
    for (int m = 0; m < 4; m++) {
      int r = wr * 64 + m * 16 + (lane & 15);
      af[m] = *(const bf16x8*)((const char*)As + r * 64 + ((lane >> 4) << 4));
    }
#pragma unroll
    for (int n = 0; n < 4; n++) {
      int r = wc * 64 + n * 16 + (lane & 15);
      bfr[n] = *(const bf16x8*)((const char*)Bs + r * 64 + ((lane >> 4) << 4));
    }
#pragma unroll
    for (int m = 0; m < 4; m++)
#pragma unroll
      for (int n = 0; n < 4; n++)
        acc[m][n] = __builtin_amdgcn_mfma_f32_16x16x32_bf16(af[m], bfr[n], acc[m][n], 0, 0, 0);
    __syncthreads();
  }

  const float* biasU = bias;
  void* coutU = Cout;
  int nloc = n0;
  if (EPI == 2 && n0 >= 1024) { biasU = bias2; coutU = Cout2; nloc = n0 - 1024; }
  float aval = (EPI == 1) ? alphap[0] : 0.f;
#pragma unroll
  for (int m = 0; m < 4; m++)
#pragma unroll
    for (int n = 0; n < 4; n++) {
      int col = nloc + wc * 64 + n * 16 + (lane & 15);
      float bv = biasU[col];
#pragma unroll
      for (int r = 0; r < 4; r++) {
        int row = m0 + wr * 64 + m * 16 + ((lane >> 4) << 2) + r;
        size_t idx = ((size_t)row << 10) + col;
        float v = acc[m][n][r] + bv;
        if (EPI == 1)
          ((float*)coutU)[idx] = resid[idx] + aval * v;
        else
          ((__bf16*)coutU)[idx] = (__bf16)v;
      }
    }
}

// ---------------- per-head RMSNorm + RoPE, bf16 in/out (used for K) ----------------
__global__ __launch_bounds__(256) void headnorm_rope_kernel(
    const __bf16* __restrict__ X, const float* __restrict__ HW,
    const float* __restrict__ COS, const float* __restrict__ SIN,
    __bf16* __restrict__ Y, int log2L, float scale) {
  int tid = threadIdx.x;
  int inst = blockIdx.x * 32 + (tid >> 3);
  int sub = tid & 7;
  int token = inst >> 4, h = inst & 15;
  int L = 1 << log2L;
  int b = token >> log2L, pos = token & (L - 1);
  const __bf16* xp = X + ((size_t)token << 10) + h * 64 + sub * 8;
  bf16x8 xv = *(const bf16x8*)xp;
  float xf[8];
#pragma unroll
  for (int i = 0; i < 8; i++) xf[i] = (float)xv[i];
  float ss = 0.f;
#pragma unroll
  for (int i = 0; i < 8; i++) ss += xf[i] * xf[i];
  ss += __shfl_xor(ss, 1);
  ss += __shfl_xor(ss, 2);
  ss += __shfl_xor(ss, 4);
  float rn = rsqrtf(ss * (1.0f / 64.0f) + 1e-6f);
  const float* hwp = HW + sub * 8;
  const float* cp = COS + ((size_t)pos << 6) + sub * 8;
  const float* sp = SIN + ((size_t)pos << 6) + sub * 8;
  float xn[8], o[8];
#pragma unroll
  for (int i = 0; i < 8; i++) xn[i] = xf[i] * rn * hwp[i];
#pragma unroll
  for (int i = 0; i < 8; i += 2) {
    float c0 = cp[i], c1 = cp[i + 1], s0 = sp[i], s1 = sp[i + 1];
    o[i] = (xn[i] * c0 - xn[i + 1] * s0) * scale;
    o[i + 1] = (xn[i + 1] * c1 + xn[i] * s1) * scale;
  }
  bf16x8 yv;
#pragma unroll
  for (int i = 0; i < 8; i++) yv[i] = (__bf16)o[i];
  *(bf16x8*)(Y + (((size_t)((b << 4) + h) << log2L) + pos) * 64 + sub * 8) = yv;
}

// ---------------- V transpose: (B*Lc,1024) token-major -> (B,16,64,Lc) ----------------
__global__ __launch_bounds__(256) void v_transpose_kernel(
    const __bf16* __restrict__ V, __bf16* __restrict__ Vt) {
  int bx = blockIdx.x;
  int bh = bx >> 4;
  int j0 = (bx & 15) * 64;
  int b = bh >> 4, h = bh & 15;
  int tid = threadIdx.x;
#pragma unroll
  for (int it = 0; it < 2; ++it) {
    int c = it * 256 + tid;
    int jl = c >> 3, d0 = (c & 7) * 8;
    bf16x8 v = *(const bf16x8*)(V + (size_t)(b * 1024 + j0 + jl) * 1024 + h * 64 + d0);
#pragma unroll
    for (int i = 0; i < 8; i++)
      Vt[((size_t)bh * 64 + d0 + i) * 1024 + j0 + jl] = v[i];
  }
}

// ---------------- flash attention, LDS-free, fused Q-prep, no-max softmax ----------------
// Qt: (B*4096,1024) bf16 token-major (raw Q-proj output)
// Kr: (B,16,1024,64) bf16 (head-normed+roped) ; Vtr: (B,16,64,1024) bf16
// AO: (B*4096,1024) bf16 token-major.
// 4 waves/block, each wave owns 32 q-rows (lane&31=q). All softmax lane-local.
// No LDS, no barriers. P = exp2(S) directly: head-RMSNorm bounds |S_log2|<=11.6.
__global__ __launch_bounds__(256, 3) void attn_kernel(
    const __bf16* __restrict__ Qt, const float* __restrict__ QHW,
    const float* __restrict__ QCOS, const float* __restrict__ QSIN,
    const __bf16* __restrict__ Kr, const __bf16* __restrict__ Vtr,
    __bf16* __restrict__ AO) {
  int tid = threadIdx.x, lane = tid & 63, w = tid >> 6;
  int lq = lane & 31, hi = lane >> 5;
  int q0 = blockIdx.x * 128;
  int bh = blockIdx.y, b = bh >> 4, h = bh & 15;
  int token = q0 + w * 32 + lq;
  const float QSC = 0.125f * 1.44269504088896340736f;  // fold 1/sqrt(64) and log2(e)

  // ---- fused Q head-RMSNorm + RoPE + scale -> bf16 B-fragments (lane's q row)
  bf16x8 qf[4];
  {
    const __bf16* qp = Qt + ((size_t)(b * 4096 + token) << 10) + h * 64 + hi * 8;
    float xf[4][8];
    float ss = 0.f;
#pragma unroll
    for (int ds = 0; ds < 4; ds++) {
      bf16x8 xv = *(const bf16x8*)(qp + ds * 16);
#pragma unroll
      for (int j = 0; j < 8; j++) { float f = (float)xv[j]; xf[ds][j] = f; ss += f * f; }
    }
    float2 sw = swap32(ss);
    float rn = rsqrtf((sw.x + sw.y) * (1.0f / 64.0f) + 1e-6f);
#pragma unroll
    for (int ds = 0; ds < 4; ds++) {
      int d0 = ds * 16 + hi * 8;
      const float* wp = QHW + d0;
      const float* cp = QCOS + ((size_t)token << 6) + d0;
      const float* sp = QSIN + ((size_t)token << 6) + d0;
      float4 wa = *(const float4*)wp, wb = *(const float4*)(wp + 4);
      float4 ca = *(const float4*)cp, cb = *(const float4*)(cp + 4);
      float4 sa = *(const float4*)sp, sb = *(const float4*)(sp + 4);
      float wv[8] = {wa.x, wa.y, wa.z, wa.w, wb.x, wb.y, wb.z, wb.w};
      float cv[8] = {ca.x, ca.y, ca.z, ca.w, cb.x, cb.y, cb.z, cb.w};
      float sv[8] = {sa.x, sa.y, sa.z, sa.w, sb.x, sb.y, sb.z, sb.w};
      float xn[8];
#pragma unroll
      for (int j = 0; j < 8; j++) xn[j] = xf[ds][j] * rn * wv[j];
      bf16x8 q8;
#pragma unroll
      for (int j = 0; j < 8; j += 2) {
        q8[j]     = (__bf16)((xn[j] * cv[j] - xn[j + 1] * sv[j]) * QSC);
        q8[j + 1] = (__bf16)((xn[j + 1] * cv[j + 1] + xn[j] * sv[j + 1]) * QSC);
      }
      qf[ds] = q8;
    }
  }

  // per-lane global fragment bases (K: A-operand rows; V: B-operand rows)
  const __bf16* kp = Kr + ((size_t)bh * 1024 + lq) * 64 + hi * 8;
  const __bf16* vp = Vtr + ((size_t)bh << 16) + (size_t)lq * 1024 + hi * 8;

  bf16x8 kf[2][4], vf[4][2];
  f32x16 accO[2];
#pragma unroll
  for (int r = 0; r < 16; r++) { accO[0][r] = 0.f; accO[1][r] = 0.f; }
  float srun = 0.f;

  // prologue: K fragments for tile 0
#pragma unroll
  for (int kt = 0; kt < 2; kt++)
#pragma unroll
    for (int ds = 0; ds < 4; ds++)
      kf[kt][ds] = *(const bf16x8*)(kp + kt * 2048 + ds * 16);

  for (int t = 0; t < 16; t++) {
    // V fragments for this tile (consumed ~400cy later in PV)
#pragma unroll
    for (int f = 0; f < 4; f++)
#pragma unroll
      for (int dh = 0; dh < 2; dh++)
        vf[f][dh] = *(const bf16x8*)(vp + dh * 32768 + t * 64 + f * 16);

    // S^T = K Q^T : col=q(lq), row=k=crow(reg,hi)
    f32x16 accS[2];
#pragma unroll
    for (int r = 0; r < 16; r++) { accS[0][r] = 0.f; accS[1][r] = 0.f; }
#pragma unroll
    for (int ds = 0; ds < 4; ds++) {
      accS[0] = __builtin_amdgcn_mfma_f32_32x32x16_bf16(kf[0][ds], qf[ds], accS[0], 0, 0, 0);
      accS[1] = __builtin_amdgcn_mfma_f32_32x32x16_bf16(kf[1][ds], qf[ds], accS[1], 0, 0, 0);
    }

    // prefetch next tile's K frags (regs free after QK; arrive during softmax+PV)
    if (t < 15) {
#pragma unroll
      for (int kt = 0; kt < 2; kt++)
#pragma unroll
        for (int ds = 0; ds < 4; ds++)
          kf[kt][ds] = *(const bf16x8*)(kp + (t + 1) * 4096 + kt * 2048 + ds * 16);
    }

    // P = exp2(S) (no max: |S| <= 11.6 by norm bound), row-sum
    float ssum = 0.f;
#pragma unroll
    for (int kt = 0; kt < 2; kt++)
#pragma unroll
      for (int r = 0; r < 16; r++) {
        float e = exp2f(accS[kt][r]);
        accS[kt][r] = e;
        ssum += e;
      }
    float2 sws = swap32(ssum);
    srun += sws.x + sws.y;

    // build P A-fragments: pack pairs, exchange halves via permlane32_swap
    unsigned pa[4][4];
#pragma unroll
    for (int kt = 0; kt < 2; kt++)
#pragma unroll
      for (int s2 = 0; s2 < 2; s2++) {
        int f = kt * 2 + s2, rb = s2 * 8;
        unsigned u  = pkbf(accS[kt][rb + 0], accS[kt][rb + 1]);
        unsigned v2 = pkbf(accS[kt][rb + 2], accS[kt][rb + 3]);
        unsigned w2 = pkbf(accS[kt][rb + 4], accS[kt][rb + 5]);
        unsigned x2 = pkbf(accS[kt][rb + 6], accS[kt][rb + 7]);
        u32x2 r02 = __builtin_amdgcn_permlane32_swap(u, w2, false, false);
        u32x2 r13 = __builtin_amdgcn_permlane32_swap(v2, x2, false, false);
        pa[f][0] = r02.x; pa[f][1] = r13.x; pa[f][2] = r02.y; pa[f][3] = r13.y;
      }

    // O^T accumulate: A=P(32q x 16k), B=V^T rows (k-contiguous)
#pragma unroll
    for (int f = 0; f < 4; f++) {
      union { unsigned u[4]; bf16x8 v; } pf;
      pf.u[0] = pa[f][0]; pf.u[1] = pa[f][1]; pf.u[2] = pa[f][2]; pf.u[3] = pa[f][3];
#pragma unroll
      for (int dh = 0; dh < 2; dh++)
        accO[dh] = __builtin_amdgcn_mfma_f32_32x32x16_bf16(pf.v, vf[f][dh], accO[dh], 0, 0, 0);
    }
  }

  // epilogue: per-q 1/sum via bpermute (q=cr lives in lane cr), bf16 stores
  float rinv = 1.0f / srun;
  int ri = __float_as_int(rinv);
  __bf16* aobase = AO + (((size_t)b * 4096) << 10) + h * 64;
#pragma unroll
  for (int r = 0; r < 16; r++) {
    int cr = (r & 3) + ((r >> 2) << 3) + (hi << 2);
    float rv = __int_as_float(__builtin_amdgcn_ds_bpermute(cr << 2, ri));
    size_t rowoff = ((size_t)(q0 + w * 32 + cr) << 10);
#pragma unroll
    for (int dh = 0; dh < 2; dh++)
      aobase[rowoff + dh * 32 + lq] = (__bf16)(accO[dh][r] * rv);
  }
}

extern "C" void kernel_launch(void* const* d_in, const int* in_sizes, int n_in,
                              void* d_out, int out_size, void* d_ws, size_t ws_size,
                              hipStream_t stream) {
  const float* img  = (const float*)d_in[0];
  const float* cnd  = (const float*)d_in[1];
  const float* qnw  = (const float*)d_in[2];
  const float* kvnw = (const float*)d_in[3];
  const float* qhw  = (const float*)d_in[4];
  const float* khw  = (const float*)d_in[5];
  const float* qw   = (const float*)d_in[6];
  const float* qb   = (const float*)d_in[7];
  const float* kw   = (const float*)d_in[8];
  const float* kb   = (const float*)d_in[9];
  const float* vw   = (const float*)d_in[10];
  const float* vb   = (const float*)d_in[11];
  const float* ow   = (const float*)d_in[12];
  const float* ob   = (const float*)d_in[13];
  const float* alpha= (const float*)d_in[14];
  const float* icos = (const float*)d_in[15];
  const float* isin = (const float*)d_in[16];
  const float* ccos = (const float*)d_in[17];
  const float* csin = (const float*)d_in[18];
  float* out = (float*)d_out;

  __bf16* p = (__bf16*)d_ws;
  __bf16* wqb = p; p += 1048576;
  __bf16* wkb = p; p += 1048576;   // wkb..wvb contiguous = (2048,1024) KV weight
  __bf16* wvb = p; p += 1048576;
  __bf16* wob = p; p += 1048576;
  __bf16* qn  = p; p += 8388608;   // (8192,1024); reused as AO after Q-GEMM consumes it
  __bf16* kvn = p; p += 2097152;
  __bf16* Qt  = p; p += 8388608;
  __bf16* Kt  = p; p += 2097152;
  __bf16* Vt0 = p; p += 2097152;
  __bf16* Kr  = p; p += 2097152;
  __bf16* Vtr = p; p += 2097152;
  __bf16* AO  = qn;  // qn dead after Q-GEMM

  rmsnorm2_kernel<<<10240, 256, 0, stream>>>(img, qnw, qn, 8192, cnd, kvnw, kvn);
  cast_w_kernel<<<2048, 256, 0, stream>>>(qw, kw, vw, ow, wqb, wkb, wvb, wob);

  gemm_bt_kernel<0><<<dim3(64, 8), 256, 0, stream>>>(qn, wqb, qb, Qt, nullptr, nullptr, nullptr, nullptr);
  gemm_bt_kernel<2><<<dim3(16, 16), 256, 0, stream>>>(kvn, wkb, kb, Kt, nullptr, nullptr, vb, Vt0);

  headnorm_rope_kernel<<<1024, 256, 0, stream>>>(Kt, khw, ccos, csin, Kr, 10, 1.0f);
  v_transpose_kernel<<<512, 256, 0, stream>>>(Vt0, Vtr);

  attn_kernel<<<dim3(32, 32), 256, 0, stream>>>(Qt, qhw, icos, isin, Kr, Vtr, AO);

  gemm_bt_kernel<1><<<dim3(64, 8), 256, 0, stream>>>(AO, wob, ob, out, img, alpha, nullptr, nullptr);
}

// Round 4
// 176.832 us; speedup vs baseline: 1.3071x; 1.3071x over previous
//
#include <hip/hip_runtime.h>

typedef __bf16 bf16x8 __attribute__((ext_vector_type(8)));
typedef __bf16 bf16x4 __attribute__((ext_vector_type(4)));
typedef float  f32x4  __attribute__((ext_vector_type(4)));
typedef float  f32x16 __attribute__((ext_vector_type(16)));
typedef unsigned u32x2 __attribute__((ext_vector_type(2)));

#define DEVINL __device__ __forceinline__

DEVINL void gload_lds16(const void* g, void* l) {
  __builtin_amdgcn_global_load_lds((const __attribute__((address_space(1))) void*)g,
                                   (__attribute__((address_space(3))) void*)l, 16, 0, 0);
}

DEVINL unsigned pkbf(float a, float b) {
  union { __bf16 h[2]; unsigned u; } c;
  c.h[0] = (__bf16)a; c.h[1] = (__bf16)b;
  return c.u;
}

// exchange lane halves: returns {x from lanes0-31 view, x from lanes32-63 view}
DEVINL float2 swap32(float x) {
  u32x2 r = __builtin_amdgcn_permlane32_swap(__float_as_uint(x), __float_as_uint(x), false, false);
  return make_float2(__uint_as_float(r.x), __uint_as_float(r.y));
}

// ---------------- RMSNorm over hidden=1024 + cast to bf16 (two tensors, one launch) ----------------
__global__ __launch_bounds__(256) void rmsnorm2_kernel(
    const float* __restrict__ XA, const float* __restrict__ WA, __bf16* __restrict__ YA, int nA,
    const float* __restrict__ XB, const float* __restrict__ WB, __bf16* __restrict__ YB) {
  int rb = blockIdx.x, tid = threadIdx.x;
  const float* X; const float* W; __bf16* Y; int row;
  if (rb < nA) { X = XA; W = WA; Y = YA; row = rb; }
  else { X = XB; W = WB; Y = YB; row = rb - nA; }
  const float4* xr = (const float4*)(X + (size_t)row * 1024);
  float4 v = xr[tid];
  float ss = v.x * v.x + v.y * v.y + v.z * v.z + v.w * v.w;
#pragma unroll
  for (int m = 1; m < 64; m <<= 1) ss += __shfl_xor(ss, m);
  __shared__ float part[4];
  if ((tid & 63) == 0) part[tid >> 6] = ss;
  __syncthreads();
  float tot = part[0] + part[1] + part[2] + part[3];
  float rn = rsqrtf(tot * (1.0f / 1024.0f) + 1e-6f);
  float4 wv = ((const float4*)W)[tid];
  bf16x4 y;
  y[0] = (__bf16)(v.x * rn * wv.x);
  y[1] = (__bf16)(v.y * rn * wv.y);
  y[2] = (__bf16)(v.z * rn * wv.z);
  y[3] = (__bf16)(v.w * rn * wv.w);
  *(bf16x4*)(Y + (size_t)row * 1024 + tid * 4) = y;
}

// ---------------- cast 4 weight matrices (1024x1024 each) to bf16 ----------------
__global__ __launch_bounds__(256) void cast_w_kernel(
    const float* __restrict__ a, const float* __restrict__ b,
    const float* __restrict__ c, const float* __restrict__ d,
    __bf16* __restrict__ oa, __bf16* __restrict__ ob,
    __bf16* __restrict__ oc, __bf16* __restrict__ od) {
  int gid = blockIdx.x * 256 + threadIdx.x;
  int which = gid >> 17;
  size_t off = (size_t)(gid & 131071) * 8;
  const float* s = (which == 0) ? a : (which == 1) ? b : (which == 2) ? c : d;
  __bf16* o = (which == 0) ? oa : (which == 1) ? ob : (which == 2) ? oc : od;
  float4 v0 = *(const float4*)(s + off), v1 = *(const float4*)(s + off + 4);
  bf16x8 y;
  y[0] = (__bf16)v0.x; y[1] = (__bf16)v0.y; y[2] = (__bf16)v0.z; y[3] = (__bf16)v0.w;
  y[4] = (__bf16)v1.x; y[5] = (__bf16)v1.y; y[6] = (__bf16)v1.z; y[7] = (__bf16)v1.w;
  *(bf16x8*)(o + off) = y;
}

// ---------------- 128x128 tile bf16 GEMM, C = A @ W^T + bias (B^T layout) ----------------
// EPI=0: bf16 out. EPI=1: f32 out = resid + alpha*(acc+bias). EPI=2: merged dual-output
// (grid.y=16 over 2048 weight rows; n0>=1024 -> bias2/Cout2).
template <int EPI>
__global__ __launch_bounds__(256) void gemm_bt_kernel(
    const __bf16* __restrict__ A, const __bf16* __restrict__ Bw,
    const float* __restrict__ bias, void* __restrict__ Cout,
    const float* __restrict__ resid, const float* __restrict__ alphap,
    const float* __restrict__ bias2, void* __restrict__ Cout2) {
  __shared__ __attribute__((aligned(16))) __bf16 As[128 * 32];
  __shared__ __attribute__((aligned(16))) __bf16 Bs[128 * 32];
  int tid = threadIdx.x, lane = tid & 63, w = tid >> 6, wr = w >> 1, wc = w & 1;
  int m0 = blockIdx.x * 128, n0 = blockIdx.y * 128;
  f32x4 z4 = {0.f, 0.f, 0.f, 0.f};
  f32x4 acc[4][4];
#pragma unroll
  for (int i = 0; i < 4; i++)
#pragma unroll
    for (int j = 0; j < 4; j++) acc[i][j] = z4;

  for (int k0 = 0; k0 < 1024; k0 += 32) {
#pragma unroll
    for (int i = 0; i < 2; i++) {
      int chunk = i * 256 + tid;
      int row = chunk >> 2, cc = chunk & 3;
      gload_lds16(A + (size_t)(m0 + row) * 1024 + k0 + cc * 8, (char*)As + i * 4096 + w * 1024);
      gload_lds16(Bw + (size_t)(n0 + row) * 1024 + k0 + cc * 8, (char*)Bs + i * 4096 + w * 1024);
    }
    __syncthreads();
    bf16x8 af[4], bfr[4];
#pragma unroll
    for (int m = 0; m < 4; m++) {
      int r = wr * 64 + m * 16 + (lane & 15);
      af[m] = *(const bf16x8*)((const char*)As + r * 64 + ((lane >> 4) << 4));
    }
#pragma unroll
    for (int n = 0; n < 4; n++) {
      int r = wc * 64 + n * 16 + (lane & 15);
      bfr[n] = *(const bf16x8*)((const char*)Bs + r * 64 + ((lane >> 4) << 4));
    }
#pragma unroll
    for (int m = 0; m < 4; m++)
#pragma unroll
      for (int n = 0; n < 4; n++)
        acc[m][n] = __builtin_amdgcn_mfma_f32_16x16x32_bf16(af[m], bfr[n], acc[m][n], 0, 0, 0);
    __syncthreads();
  }

  const float* biasU = bias;
  void* coutU = Cout;
  int nloc = n0;
  if (EPI == 2 && n0 >= 1024) { biasU = bias2; coutU = Cout2; nloc = n0 - 1024; }
  float aval = (EPI == 1) ? alphap[0] : 0.f;
#pragma unroll
  for (int m = 0; m < 4; m++)
#pragma unroll
    for (int n = 0; n < 4; n++) {
      int col = nloc + wc * 64 + n * 16 + (lane & 15);
      float bv = biasU[col];
#pragma unroll
      for (int r = 0; r < 4; r++) {
        int row = m0 + wr * 64 + m * 16 + ((lane >> 4) << 2) + r;
        size_t idx = ((size_t)row << 10) + col;
        float v = acc[m][n][r] + bv;
        if (EPI == 1)
          ((float*)coutU)[idx] = resid[idx] + aval * v;
        else
          ((__bf16*)coutU)[idx] = (__bf16)v;
      }
    }
}

// ---------------- per-head RMSNorm + RoPE, bf16 in/out (used for K) ----------------
__global__ __launch_bounds__(256) void headnorm_rope_kernel(
    const __bf16* __restrict__ X, const float* __restrict__ HW,
    const float* __restrict__ COS, const float* __restrict__ SIN,
    __bf16* __restrict__ Y, int log2L, float scale) {
  int tid = threadIdx.x;
  int inst = blockIdx.x * 32 + (tid >> 3);
  int sub = tid & 7;
  int token = inst >> 4, h = inst & 15;
  int L = 1 << log2L;
  int b = token >> log2L, pos = token & (L - 1);
  const __bf16* xp = X + ((size_t)token << 10) + h * 64 + sub * 8;
  bf16x8 xv = *(const bf16x8*)xp;
  float xf[8];
#pragma unroll
  for (int i = 0; i < 8; i++) xf[i] = (float)xv[i];
  float ss = 0.f;
#pragma unroll
  for (int i = 0; i < 8; i++) ss += xf[i] * xf[i];
  ss += __shfl_xor(ss, 1);
  ss += __shfl_xor(ss, 2);
  ss += __shfl_xor(ss, 4);
  float rn = rsqrtf(ss * (1.0f / 64.0f) + 1e-6f);
  const float* hwp = HW + sub * 8;
  const float* cp = COS + ((size_t)pos << 6) + sub * 8;
  const float* sp = SIN + ((size_t)pos << 6) + sub * 8;
  float xn[8], o[8];
#pragma unroll
  for (int i = 0; i < 8; i++) xn[i] = xf[i] * rn * hwp[i];
#pragma unroll
  for (int i = 0; i < 8; i += 2) {
    float c0 = cp[i], c1 = cp[i + 1], s0 = sp[i], s1 = sp[i + 1];
    o[i] = (xn[i] * c0 - xn[i + 1] * s0) * scale;
    o[i + 1] = (xn[i + 1] * c1 + xn[i] * s1) * scale;
  }
  bf16x8 yv;
#pragma unroll
  for (int i = 0; i < 8; i++) yv[i] = (__bf16)o[i];
  *(bf16x8*)(Y + (((size_t)((b << 4) + h) << log2L) + pos) * 64 + sub * 8) = yv;
}

// ---------------- V transpose: (B*Lc,1024) token-major -> (B,16,64,Lc) ----------------
__global__ __launch_bounds__(256) void v_transpose_kernel(
    const __bf16* __restrict__ V, __bf16* __restrict__ Vt) {
  int bx = blockIdx.x;
  int bh = bx >> 4;
  int j0 = (bx & 15) * 64;
  int b = bh >> 4, h = bh & 15;
  int tid = threadIdx.x;
#pragma unroll
  for (int it = 0; it < 2; ++it) {
    int c = it * 256 + tid;
    int jl = c >> 3, d0 = (c & 7) * 8;
    bf16x8 v = *(const bf16x8*)(V + (size_t)(b * 1024 + j0 + jl) * 1024 + h * 64 + d0);
#pragma unroll
    for (int i = 0; i < 8; i++)
      Vt[((size_t)bh * 64 + d0 + i) * 1024 + j0 + jl] = v[i];
  }
}

// ---------------- flash attention: fragment-linear LDS staging, 64q/wave ----------------
// Qt: (B*4096,1024) bf16 token-major (raw Q-proj output)
// Kr: (B,16,1024,64) bf16 (head-normed+roped) ; Vtr: (B,16,64,1024) bf16
// AO: (B*4096,1024) bf16 token-major.
// 4 waves/block, each wave owns 64 q-rows (2 subtiles of 32; lane&31=q).
// K/V tiles staged in MFMA-fragment order: 8 slots x (64 lanes x 16B) = 8KB each.
// Slot source address = exactly the element the reading lane needs -> ds_read_b128
// at slot*1024 + lane*16 is linear and bank-conflict-free (rule #21: linear LDS
// dest + permuted global source). P = exp2(S) directly (head-RMSNorm bounds |S|).
__global__ __launch_bounds__(256, 2) void attn_kernel(
    const __bf16* __restrict__ Qt, const float* __restrict__ QHW,
    const float* __restrict__ QCOS, const float* __restrict__ QSIN,
    const __bf16* __restrict__ Kr, const __bf16* __restrict__ Vtr,
    __bf16* __restrict__ AO) {
  int tid = threadIdx.x, lane = tid & 63, w = tid >> 6;
  int lq = lane & 31, hi = lane >> 5;
  int q0 = blockIdx.x * 256;
  int bh = blockIdx.y, b = bh >> 4, h = bh & 15;
  const float QSC = 0.125f * 1.44269504088896340736f;  // 1/sqrt(64) * log2(e)

  __shared__ __attribute__((aligned(16))) __bf16 Ks[2][4096];
  __shared__ __attribute__((aligned(16))) __bf16 Vs[2][4096];

  const __bf16* Kbh = Kr + ((size_t)bh << 16);
  const __bf16* Vbh = Vtr + ((size_t)bh << 16);

  // stage tile 0 into buf 0 (each wave stages slots 2w, 2w+1 of K and V)
#pragma unroll
  for (int i = 0; i < 2; i++) {
    int s = 2 * w + i;
    int kt = s >> 2, ds = s & 3;
    gload_lds16(Kbh + (size_t)(kt * 32 + lq) * 64 + ds * 16 + hi * 8,
                (char*)Ks[0] + s * 1024);
    int f = s >> 1, dh = s & 1;
    gload_lds16(Vbh + (size_t)(dh * 32 + lq) * 1024 + f * 16 + hi * 8,
                (char*)Vs[0] + s * 1024);
  }

  // ---- fused Q head-RMSNorm + RoPE + scale for both q-subtiles (overlaps staging)
  bf16x8 qf[2][4];
#pragma unroll
  for (int qt = 0; qt < 2; qt++) {
    int pos = q0 + w * 64 + qt * 32 + lq;
    const __bf16* qp = Qt + ((size_t)(b * 4096 + pos) << 10) + h * 64 + hi * 8;
    float xf[4][8];
    float ss = 0.f;
#pragma unroll
    for (int ds = 0; ds < 4; ds++) {
      bf16x8 xv = *(const bf16x8*)(qp + ds * 16);
#pragma unroll
      for (int j = 0; j < 8; j++) { float f = (float)xv[j]; xf[ds][j] = f; ss += f * f; }
    }
    float2 sw = swap32(ss);
    float rn = rsqrtf((sw.x + sw.y) * (1.0f / 64.0f) + 1e-6f);
#pragma unroll
    for (int ds = 0; ds < 4; ds++) {
      int d0 = ds * 16 + hi * 8;
      const float* wp = QHW + d0;
      const float* cp = QCOS + ((size_t)pos << 6) + d0;
      const float* sp = QSIN + ((size_t)pos << 6) + d0;
      float4 wa = *(const float4*)wp, wb = *(const float4*)(wp + 4);
      float4 ca = *(const float4*)cp, cb = *(const float4*)(cp + 4);
      float4 sa = *(const float4*)sp, sb = *(const float4*)(sp + 4);
      float wv[8] = {wa.x, wa.y, wa.z, wa.w, wb.x, wb.y, wb.z, wb.w};
      float cv[8] = {ca.x, ca.y, ca.z, ca.w, cb.x, cb.y, cb.z, cb.w};
      float sv[8] = {sa.x, sa.y, sa.z, sa.w, sb.x, sb.y, sb.z, sb.w};
      float xn[8];
#pragma unroll
      for (int j = 0; j < 8; j++) xn[j] = xf[ds][j] * rn * wv[j];
      bf16x8 q8;
#pragma unroll
      for (int j = 0; j < 8; j += 2) {
        q8[j]     = (__bf16)((xn[j] * cv[j] - xn[j + 1] * sv[j]) * QSC);
        q8[j + 1] = (__bf16)((xn[j + 1] * cv[j + 1] + xn[j] * sv[j + 1]) * QSC);
      }
      qf[qt][ds] = q8;
    }
  }

  f32x16 accO[2][2];  // [qt][dh]
#pragma unroll
  for (int qt = 0; qt < 2; qt++)
#pragma unroll
    for (int dh = 0; dh < 2; dh++)
#pragma unroll
      for (int r = 0; r < 16; r++) accO[qt][dh][r] = 0.f;
  float srun[2] = {0.f, 0.f};

  __syncthreads();

  int buf = 0;
  for (int t = 0; t < 16; t++) {
    // prefetch tile t+1 into buf^1 (drained by the barrier at loop end)
    if (t < 15) {
#pragma unroll
      for (int i = 0; i < 2; i++) {
        int s = 2 * w + i;
        int kt = s >> 2, ds = s & 3;
        gload_lds16(Kbh + (size_t)((t + 1) * 64 + kt * 32 + lq) * 64 + ds * 16 + hi * 8,
                    (char*)Ks[buf ^ 1] + s * 1024);
        int f = s >> 1, dh = s & 1;
        gload_lds16(Vbh + (size_t)(dh * 32 + lq) * 1024 + (t + 1) * 64 + f * 16 + hi * 8,
                    (char*)Vs[buf ^ 1] + s * 1024);
      }
    }
    const char* kbase = (const char*)Ks[buf];
    const char* vbase = (const char*)Vs[buf];
    int loff = lane * 16;

    // K fragments: 8 linear ds_read_b128 (slot s = kt*4+ds)
    bf16x8 kf[8];
#pragma unroll
    for (int s = 0; s < 8; s++) kf[s] = *(const bf16x8*)(kbase + s * 1024 + loff);

    // S^T = K Q^T per q-subtile: col=q(lq), row=k
    f32x16 accS[2][2];
#pragma unroll
    for (int qt = 0; qt < 2; qt++)
#pragma unroll
      for (int kt = 0; kt < 2; kt++)
#pragma unroll
        for (int r = 0; r < 16; r++) accS[qt][kt][r] = 0.f;
#pragma unroll
    for (int qt = 0; qt < 2; qt++)
#pragma unroll
      for (int ds = 0; ds < 4; ds++) {
        accS[qt][0] = __builtin_amdgcn_mfma_f32_32x32x16_bf16(kf[ds], qf[qt][ds], accS[qt][0], 0, 0, 0);
        accS[qt][1] = __builtin_amdgcn_mfma_f32_32x32x16_bf16(kf[4 + ds], qf[qt][ds], accS[qt][1], 0, 0, 0);
      }

    // P = exp2(S), row-sums, pack to A-fragments (permlane32_swap half-exchange)
    unsigned pa[2][4][4];
#pragma unroll
    for (int qt = 0; qt < 2; qt++) {
      float ssum = 0.f;
#pragma unroll
      for (int kt = 0; kt < 2; kt++)
#pragma unroll
        for (int r = 0; r < 16; r++) {
          float e = exp2f(accS[qt][kt][r]);
          accS[qt][kt][r] = e;
          ssum += e;
        }
      float2 sws = swap32(ssum);
      srun[qt] += sws.x + sws.y;
#pragma unroll
      for (int kt = 0; kt < 2; kt++)
#pragma unroll
        for (int s2 = 0; s2 < 2; s2++) {
          int f = kt * 2 + s2, rb = s2 * 8;
          unsigned u  = pkbf(accS[qt][kt][rb + 0], accS[qt][kt][rb + 1]);
          unsigned v2 = pkbf(accS[qt][kt][rb + 2], accS[qt][kt][rb + 3]);
          unsigned w2 = pkbf(accS[qt][kt][rb + 4], accS[qt][kt][rb + 5]);
          unsigned x2 = pkbf(accS[qt][kt][rb + 6], accS[qt][kt][rb + 7]);
          u32x2 r02 = __builtin_amdgcn_permlane32_swap(u, w2, false, false);
          u32x2 r13 = __builtin_amdgcn_permlane32_swap(v2, x2, false, false);
          pa[qt][f][0] = r02.x; pa[qt][f][1] = r13.x; pa[qt][f][2] = r02.y; pa[qt][f][3] = r13.y;
        }
    }

    // V fragments: 8 linear ds_read_b128 (slot s = f*2+dh)
    bf16x8 vf[8];
#pragma unroll
    for (int s = 0; s < 8; s++) vf[s] = *(const bf16x8*)(vbase + s * 1024 + loff);

    // O^T accumulate
#pragma unroll
    for (int f = 0; f < 4; f++)
#pragma unroll
      for (int qt = 0; qt < 2; qt++) {
        union { unsigned u[4]; bf16x8 v; } pf;
        pf.u[0] = pa[qt][f][0]; pf.u[1] = pa[qt][f][1];
        pf.u[2] = pa[qt][f][2]; pf.u[3] = pa[qt][f][3];
#pragma unroll
        for (int dh = 0; dh < 2; dh++)
          accO[qt][dh] = __builtin_amdgcn_mfma_f32_32x32x16_bf16(pf.v, vf[f * 2 + dh], accO[qt][dh], 0, 0, 0);
      }
    __syncthreads();
    buf ^= 1;
  }

  // epilogue: per-q 1/sum via bpermute (q col cr lives in lane cr), bf16 stores
  __bf16* aobase = AO + (((size_t)b * 4096) << 10) + h * 64;
#pragma unroll
  for (int qt = 0; qt < 2; qt++) {
    float rinv = 1.0f / srun[qt];
    int ri = __float_as_int(rinv);
#pragma unroll
    for (int r = 0; r < 16; r++) {
      int cr = (r & 3) + ((r >> 2) << 3) + (hi << 2);
      float rv = __int_as_float(__builtin_amdgcn_ds_bpermute(cr << 2, ri));
      size_t rowoff = ((size_t)(q0 + w * 64 + qt * 32 + cr) << 10);
#pragma unroll
      for (int dh = 0; dh < 2; dh++)
        aobase[rowoff + dh * 32 + lq] = (__bf16)(accO[qt][dh][r] * rv);
    }
  }
}

extern "C" void kernel_launch(void* const* d_in, const int* in_sizes, int n_in,
                              void* d_out, int out_size, void* d_ws, size_t ws_size,
                              hipStream_t stream) {
  const float* img  = (const float*)d_in[0];
  const float* cnd  = (const float*)d_in[1];
  const float* qnw  = (const float*)d_in[2];
  const float* kvnw = (const float*)d_in[3];
  const float* qhw  = (const float*)d_in[4];
  const float* khw  = (const float*)d_in[5];
  const float* qw   = (const float*)d_in[6];
  const float* qb   = (const float*)d_in[7];
  const float* kw   = (const float*)d_in[8];
  const float* kb   = (const float*)d_in[9];
  const float* vw   = (const float*)d_in[10];
  const float* vb   = (const float*)d_in[11];
  const float* ow   = (const float*)d_in[12];
  const float* ob   = (const float*)d_in[13];
  const float* alpha= (const float*)d_in[14];
  const float* icos = (const float*)d_in[15];
  const float* isin = (const float*)d_in[16];
  const float* ccos = (const float*)d_in[17];
  const float* csin = (const float*)d_in[18];
  float* out = (float*)d_out;

  __bf16* p = (__bf16*)d_ws;
  __bf16* wqb = p; p += 1048576;
  __bf16* wkb = p; p += 1048576;   // wkb..wvb contiguous = (2048,1024) KV weight
  __bf16* wvb = p; p += 1048576;
  __bf16* wob = p; p += 1048576;
  __bf16* qn  = p; p += 8388608;   // (8192,1024); reused as AO after Q-GEMM consumes it
  __bf16* kvn = p; p += 2097152;
  __bf16* Qt  = p; p += 8388608;
  __bf16* Kt  = p; p += 2097152;
  __bf16* Vt0 = p; p += 2097152;
  __bf16* Kr  = p; p += 2097152;
  __bf16* Vtr = p; p += 2097152;
  __bf16* AO  = qn;  // qn dead after Q-GEMM

  rmsnorm2_kernel<<<10240, 256, 0, stream>>>(img, qnw, qn, 8192, cnd, kvnw, kvn);
  cast_w_kernel<<<2048, 256, 0, stream>>>(qw, kw, vw, ow, wqb, wkb, wvb, wob);

  gemm_bt_kernel<0><<<dim3(64, 8), 256, 0, stream>>>(qn, wqb, qb, Qt, nullptr, nullptr, nullptr, nullptr);
  gemm_bt_kernel<2><<<dim3(16, 16), 256, 0, stream>>>(kvn, wkb, kb, Kt, nullptr, nullptr, vb, Vt0);

  headnorm_rope_kernel<<<1024, 256, 0, stream>>>(Kt, khw, ccos, csin, Kr, 10, 1.0f);
  v_transpose_kernel<<<512, 256, 0, stream>>>(Vt0, Vtr);

  attn_kernel<<<dim3(16, 32), 256, 0, stream>>>(Qt, qhw, icos, isin, Kr, Vtr, AO);

  gemm_bt_kernel<1><<<dim3(64, 8), 256, 0, stream>>>(AO, wob, ob, out, img, alpha, nullptr, nullptr);
}

// Round 5
// 162.064 us; speedup vs baseline: 1.4262x; 1.0911x over previous
//
#include <hip/hip_runtime.h>

typedef __bf16 bf16x8 __attribute__((ext_vector_type(8)));
typedef __bf16 bf16x4 __attribute__((ext_vector_type(4)));
typedef float  f32x4  __attribute__((ext_vector_type(4)));
typedef float  f32x16 __attribute__((ext_vector_type(16)));
typedef unsigned u32x2 __attribute__((ext_vector_type(2)));

#define DEVINL __device__ __forceinline__

DEVINL void gload_lds16(const void* g, void* l) {
  __builtin_amdgcn_global_load_lds((const __attribute__((address_space(1))) void*)g,
                                   (__attribute__((address_space(3))) void*)l, 16, 0, 0);
}

DEVINL unsigned pkbf(float a, float b) {
  union { __bf16 h[2]; unsigned u; } c;
  c.h[0] = (__bf16)a; c.h[1] = (__bf16)b;
  return c.u;
}

// raw v_exp_f32 (exact for |x|<=12 domain; skips OCML denorm fixup)
DEVINL float fast_exp2(float x) {
#if __has_builtin(__builtin_amdgcn_exp2f)
  return __builtin_amdgcn_exp2f(x);
#else
  float r;
  asm volatile("v_exp_f32 %0, %1" : "=v"(r) : "v"(x));
  return r;
#endif
}

// exchange lane halves: returns {x from lanes0-31 view, x from lanes32-63 view}
DEVINL float2 swap32(float x) {
  u32x2 r = __builtin_amdgcn_permlane32_swap(__float_as_uint(x), __float_as_uint(x), false, false);
  return make_float2(__uint_as_float(r.x), __uint_as_float(r.y));
}

// ---------------- RMSNorm over hidden=1024 + cast to bf16 (two tensors, one launch) ----------------
__global__ __launch_bounds__(256) void rmsnorm2_kernel(
    const float* __restrict__ XA, const float* __restrict__ WA, __bf16* __restrict__ YA, int nA,
    const float* __restrict__ XB, const float* __restrict__ WB, __bf16* __restrict__ YB) {
  int rb = blockIdx.x, tid = threadIdx.x;
  const float* X; const float* W; __bf16* Y; int row;
  if (rb < nA) { X = XA; W = WA; Y = YA; row = rb; }
  else { X = XB; W = WB; Y = YB; row = rb - nA; }
  const float4* xr = (const float4*)(X + (size_t)row * 1024);
  float4 v = xr[tid];
  float ss = v.x * v.x + v.y * v.y + v.z * v.z + v.w * v.w;
#pragma unroll
  for (int m = 1; m < 64; m <<= 1) ss += __shfl_xor(ss, m);
  __shared__ float part[4];
  if ((tid & 63) == 0) part[tid >> 6] = ss;
  __syncthreads();
  float tot = part[0] + part[1] + part[2] + part[3];
  float rn = rsqrtf(tot * (1.0f / 1024.0f) + 1e-6f);
  float4 wv = ((const float4*)W)[tid];
  bf16x4 y;
  y[0] = (__bf16)(v.x * rn * wv.x);
  y[1] = (__bf16)(v.y * rn * wv.y);
  y[2] = (__bf16)(v.z * rn * wv.z);
  y[3] = (__bf16)(v.w * rn * wv.w);
  *(bf16x4*)(Y + (size_t)row * 1024 + tid * 4) = y;
}

// ---------------- cast 4 weight matrices (1024x1024 each) to bf16 ----------------
__global__ __launch_bounds__(256) void cast_w_kernel(
    const float* __restrict__ a, const float* __restrict__ b,
    const float* __restrict__ c, const float* __restrict__ d,
    __bf16* __restrict__ oa, __bf16* __restrict__ ob,
    __bf16* __restrict__ oc, __bf16* __restrict__ od) {
  int gid = blockIdx.x * 256 + threadIdx.x;
  int which = gid >> 17;
  size_t off = (size_t)(gid & 131071) * 8;
  const float* s = (which == 0) ? a : (which == 1) ? b : (which == 2) ? c : d;
  __bf16* o = (which == 0) ? oa : (which == 1) ? ob : (which == 2) ? oc : od;
  float4 v0 = *(const float4*)(s + off), v1 = *(const float4*)(s + off + 4);
  bf16x8 y;
  y[0] = (__bf16)v0.x; y[1] = (__bf16)v0.y; y[2] = (__bf16)v0.z; y[3] = (__bf16)v0.w;
  y[4] = (__bf16)v1.x; y[5] = (__bf16)v1.y; y[6] = (__bf16)v1.z; y[7] = (__bf16)v1.w;
  *(bf16x8*)(o + off) = y;
}

// ---------------- 128x128 tile bf16 GEMM, C = A @ W^T + bias (B^T layout) ----------------
// EPI=0: bf16 out. EPI=1: f32 out = resid + alpha*(acc+bias). EPI=2: merged dual-output
// (grid.y=16 over 2048 weight rows; n0>=1024 -> bias2/Cout2).
template <int EPI>
__global__ __launch_bounds__(256) void gemm_bt_kernel(
    const __bf16* __restrict__ A, const __bf16* __restrict__ Bw,
    const float* __restrict__ bias, void* __restrict__ Cout,
    const float* __restrict__ resid, const float* __restrict__ alphap,
    const float* __restrict__ bias2, void* __restrict__ Cout2) {
  __shared__ __attribute__((aligned(16))) __bf16 As[128 * 32];
  __shared__ __attribute__((aligned(16))) __bf16 Bs[128 * 32];
  int tid = threadIdx.x, lane = tid & 63, w = tid >> 6, wr = w >> 1, wc = w & 1;
  int m0 = blockIdx.x * 128, n0 = blockIdx.y * 128;
  f32x4 z4 = {0.f, 0.f, 0.f, 0.f};
  f32x4 acc[4][4];
#pragma unroll
  for (int i = 0; i < 4; i++)
#pragma unroll
    for (int j = 0; j < 4; j++) acc[i][j] = z4;

  for (int k0 = 0; k0 < 1024; k0 += 32) {
#pragma unroll
    for (int i = 0; i < 2; i++) {
      int chunk = i * 256 + tid;
      int row = chunk >> 2, cc = chunk & 3;
      gload_lds16(A + (size_t)(m0 + row) * 1024 + k0 + cc * 8, (char*)As + i * 4096 + w * 1024);
      gload_lds16(Bw + (size_t)(n0 + row) * 1024 + k0 + cc * 8, (char*)Bs + i * 4096 + w * 1024);
    }
    __syncthreads();
    bf16x8 af[4], bfr[4];
#pragma unroll
    for (int m = 0; m < 4; m++) {
      int r = wr * 64 + m * 16 + (lane & 15);
      af[m] = *(const bf16x8*)((const char*)As + r * 64 + ((lane >> 4) << 4));
    }
#pragma unroll
    for (int n = 0; n < 4; n++) {
      int r = wc * 64 + n * 16 + (lane & 15);
      bfr[n] = *(const bf16x8*)((const char*)Bs + r * 64 + ((lane >> 4) << 4));
    }
#pragma unroll
    for (int m = 0; m < 4; m++)
#pragma unroll
      for (int n = 0; n < 4; n++)
        acc[m][n] = __builtin_amdgcn_mfma_f32_16x16x32_bf16(af[m], bfr[n], acc[m][n], 0, 0, 0);
    __syncthreads();
  }

  const float* biasU = bias;
  void* coutU = Cout;
  int nloc = n0;
  if (EPI == 2 && n0 >= 1024) { biasU = bias2; coutU = Cout2; nloc = n0 - 1024; }
  float aval = (EPI == 1) ? alphap[0] : 0.f;
#pragma unroll
  for (int m = 0; m < 4; m++)
#pragma unroll
    for (int n = 0; n < 4; n++) {
      int col = nloc + wc * 64 + n * 16 + (lane & 15);
      float bv = biasU[col];
#pragma unroll
      for (int r = 0; r < 4; r++) {
        int row = m0 + wr * 64 + m * 16 + ((lane >> 4) << 2) + r;
        size_t idx = ((size_t)row << 10) + col;
        float v = acc[m][n][r] + bv;
        if (EPI == 1)
          ((float*)coutU)[idx] = resid[idx] + aval * v;
        else
          ((__bf16*)coutU)[idx] = (__bf16)v;
      }
    }
}

// ---------------- per-head RMSNorm + RoPE, bf16 in/out (used for K) ----------------
__global__ __launch_bounds__(256) void headnorm_rope_kernel(
    const __bf16* __restrict__ X, const float* __restrict__ HW,
    const float* __restrict__ COS, const float* __restrict__ SIN,
    __bf16* __restrict__ Y, int log2L, float scale) {
  int tid = threadIdx.x;
  int inst = blockIdx.x * 32 + (tid >> 3);
  int sub = tid & 7;
  int token = inst >> 4, h = inst & 15;
  int L = 1 << log2L;
  int b = token >> log2L, pos = token & (L - 1);
  const __bf16* xp = X + ((size_t)token << 10) + h * 64 + sub * 8;
  bf16x8 xv = *(const bf16x8*)xp;
  float xf[8];
#pragma unroll
  for (int i = 0; i < 8; i++) xf[i] = (float)xv[i];
  float ss = 0.f;
#pragma unroll
  for (int i = 0; i < 8; i++) ss += xf[i] * xf[i];
  ss += __shfl_xor(ss, 1);
  ss += __shfl_xor(ss, 2);
  ss += __shfl_xor(ss, 4);
  float rn = rsqrtf(ss * (1.0f / 64.0f) + 1e-6f);
  const float* hwp = HW + sub * 8;
  const float* cp = COS + ((size_t)pos << 6) + sub * 8;
  const float* sp = SIN + ((size_t)pos << 6) + sub * 8;
  float xn[8], o[8];
#pragma unroll
  for (int i = 0; i < 8; i++) xn[i] = xf[i] * rn * hwp[i];
#pragma unroll
  for (int i = 0; i < 8; i += 2) {
    float c0 = cp[i], c1 = cp[i + 1], s0 = sp[i], s1 = sp[i + 1];
    o[i] = (xn[i] * c0 - xn[i + 1] * s0) * scale;
    o[i + 1] = (xn[i + 1] * c1 + xn[i] * s1) * scale;
  }
  bf16x8 yv;
#pragma unroll
  for (int i = 0; i < 8; i++) yv[i] = (__bf16)o[i];
  *(bf16x8*)(Y + (((size_t)((b << 4) + h) << log2L) + pos) * 64 + sub * 8) = yv;
}

// ---------------- V transpose: (B*Lc,1024) token-major -> (B,16,64,Lc) ----------------
__global__ __launch_bounds__(256) void v_transpose_kernel(
    const __bf16* __restrict__ V, __bf16* __restrict__ Vt) {
  int bx = blockIdx.x;
  int bh = bx >> 4;
  int j0 = (bx & 15) * 64;
  int b = bh >> 4, h = bh & 15;
  int tid = threadIdx.x;
#pragma unroll
  for (int it = 0; it < 2; ++it) {
    int c = it * 256 + tid;
    int jl = c >> 3, d0 = (c & 7) * 8;
    bf16x8 v = *(const bf16x8*)(V + (size_t)(b * 1024 + j0 + jl) * 1024 + h * 64 + d0);
#pragma unroll
    for (int i = 0; i < 8; i++)
      Vt[((size_t)bh * 64 + d0 + i) * 1024 + j0 + jl] = v[i];
  }
}

// ---------------- flash attention: fragment-linear LDS staging, 64q/wave ----------------
// Qt: (B*4096,1024) bf16 token-major (raw Q-proj output)
// Kr: (B,16,1024,64) bf16 (head-normed+roped) ; Vtr: (B,16,64,1024) bf16
// AO: (B*4096,1024) bf16 token-major.
// 4 waves/block, each wave owns 64 q-rows (2 subtiles of 32; lane&31=q).
// K/V tiles staged in MFMA-fragment order (8 slots x 1KB): linear ds_read_b128,
// zero bank conflicts (rule #21: linear LDS dest + permuted global source).
// P = exp2(S) directly via raw v_exp_f32 (head-RMSNorm bounds |S|<=11.6).
__global__ __launch_bounds__(256, 2) void attn_kernel(
    const __bf16* __restrict__ Qt, const float* __restrict__ QHW,
    const float* __restrict__ QCOS, const float* __restrict__ QSIN,
    const __bf16* __restrict__ Kr, const __bf16* __restrict__ Vtr,
    __bf16* __restrict__ AO) {
  int tid = threadIdx.x, lane = tid & 63, w = tid >> 6;
  int lq = lane & 31, hi = lane >> 5;
  int q0 = blockIdx.x * 256;
  int bh = blockIdx.y, b = bh >> 4, h = bh & 15;
  const float QSC = 0.125f * 1.44269504088896340736f;  // 1/sqrt(64) * log2(e)

  __shared__ __attribute__((aligned(16))) __bf16 Ks[2][4096];
  __shared__ __attribute__((aligned(16))) __bf16 Vs[2][4096];

  const __bf16* Kbh = Kr + ((size_t)bh << 16);
  const __bf16* Vbh = Vtr + ((size_t)bh << 16);

  // stage tile 0 into buf 0 (each wave stages slots 2w, 2w+1 of K and V)
#pragma unroll
  for (int i = 0; i < 2; i++) {
    int s = 2 * w + i;
    int kt = s >> 2, ds = s & 3;
    gload_lds16(Kbh + (size_t)(kt * 32 + lq) * 64 + ds * 16 + hi * 8,
                (char*)Ks[0] + s * 1024);
    int f = s >> 1, dh = s & 1;
    gload_lds16(Vbh + (size_t)(dh * 32 + lq) * 1024 + f * 16 + hi * 8,
                (char*)Vs[0] + s * 1024);
  }

  // ---- fused Q head-RMSNorm + RoPE + scale for both q-subtiles (overlaps staging)
  bf16x8 qf[2][4];
#pragma unroll
  for (int qt = 0; qt < 2; qt++) {
    int pos = q0 + w * 64 + qt * 32 + lq;
    const __bf16* qp = Qt + ((size_t)(b * 4096 + pos) << 10) + h * 64 + hi * 8;
    float xf[4][8];
    float ss = 0.f;
#pragma unroll
    for (int ds = 0; ds < 4; ds++) {
      bf16x8 xv = *(const bf16x8*)(qp + ds * 16);
#pragma unroll
      for (int j = 0; j < 8; j++) { float f = (float)xv[j]; xf[ds][j] = f; ss += f * f; }
    }
    float2 sw = swap32(ss);
    float rn = rsqrtf((sw.x + sw.y) * (1.0f / 64.0f) + 1e-6f);
#pragma unroll
    for (int ds = 0; ds < 4; ds++) {
      int d0 = ds * 16 + hi * 8;
      const float* wp = QHW + d0;
      const float* cp = QCOS + ((size_t)pos << 6) + d0;
      const float* sp = QSIN + ((size_t)pos << 6) + d0;
      float4 wa = *(const float4*)wp, wb = *(const float4*)(wp + 4);
      float4 ca = *(const float4*)cp, cb = *(const float4*)(cp + 4);
      float4 sa = *(const float4*)sp, sb = *(const float4*)(sp + 4);
      float wv[8] = {wa.x, wa.y, wa.z, wa.w, wb.x, wb.y, wb.z, wb.w};
      float cv[8] = {ca.x, ca.y, ca.z, ca.w, cb.x, cb.y, cb.z, cb.w};
      float sv[8] = {sa.x, sa.y, sa.z, sa.w, sb.x, sb.y, sb.z, sb.w};
      float xn[8];
#pragma unroll
      for (int j = 0; j < 8; j++) xn[j] = xf[ds][j] * rn * wv[j];
      bf16x8 q8;
#pragma unroll
      for (int j = 0; j < 8; j += 2) {
        q8[j]     = (__bf16)((xn[j] * cv[j] - xn[j + 1] * sv[j]) * QSC);
        q8[j + 1] = (__bf16)((xn[j + 1] * cv[j + 1] + xn[j] * sv[j + 1]) * QSC);
      }
      qf[qt][ds] = q8;
    }
  }

  // persistent zero accumulator: first MFMA of each group uses it as C
  f32x16 Z16;
#pragma unroll
  for (int r = 0; r < 16; r++) Z16[r] = 0.f;

  f32x16 accO[2][2];  // [qt][dh]
#pragma unroll
  for (int qt = 0; qt < 2; qt++)
#pragma unroll
    for (int dh = 0; dh < 2; dh++) accO[qt][dh] = Z16;
  float srun[2] = {0.f, 0.f};

  __syncthreads();

  int buf = 0;
  for (int t = 0; t < 16; t++) {
    // prefetch tile t+1 into buf^1 (drained by the barrier at loop end)
    if (t < 15) {
#pragma unroll
      for (int i = 0; i < 2; i++) {
        int s = 2 * w + i;
        int kt = s >> 2, ds = s & 3;
        gload_lds16(Kbh + (size_t)((t + 1) * 64 + kt * 32 + lq) * 64 + ds * 16 + hi * 8,
                    (char*)Ks[buf ^ 1] + s * 1024);
        int f = s >> 1, dh = s & 1;
        gload_lds16(Vbh + (size_t)(dh * 32 + lq) * 1024 + (t + 1) * 64 + f * 16 + hi * 8,
                    (char*)Vs[buf ^ 1] + s * 1024);
      }
    }
    const char* kbase = (const char*)Ks[buf];
    const char* vbase = (const char*)Vs[buf];
    int loff = lane * 16;

    // all LDS fragment reads issued up front: K (QK waits lgkm) then V (PV waits)
    bf16x8 kf[8], vf[8];
#pragma unroll
    for (int s = 0; s < 8; s++) kf[s] = *(const bf16x8*)(kbase + s * 1024 + loff);
#pragma unroll
    for (int s = 0; s < 8; s++) vf[s] = *(const bf16x8*)(vbase + s * 1024 + loff);

    // S^T = K Q^T per q-subtile: col=q(lq), row=k  (first MFMA consumes Z16)
    f32x16 accS[2][2];
    __builtin_amdgcn_s_setprio(1);
#pragma unroll
    for (int qt = 0; qt < 2; qt++)
#pragma unroll
      for (int kt = 0; kt < 2; kt++) {
        accS[qt][kt] = __builtin_amdgcn_mfma_f32_32x32x16_bf16(kf[kt * 4], qf[qt][0], Z16, 0, 0, 0);
#pragma unroll
        for (int ds = 1; ds < 4; ds++)
          accS[qt][kt] = __builtin_amdgcn_mfma_f32_32x32x16_bf16(kf[kt * 4 + ds], qf[qt][ds], accS[qt][kt], 0, 0, 0);
      }
    __builtin_amdgcn_s_setprio(0);

    // P = exp2(S) (raw v_exp_f32), row-sums, pack to A-frags (permlane32_swap)
    unsigned pa[2][4][4];
#pragma unroll
    for (int qt = 0; qt < 2; qt++) {
      float ssum = 0.f;
#pragma unroll
      for (int kt = 0; kt < 2; kt++)
#pragma unroll
        for (int r = 0; r < 16; r++) {
          float e = fast_exp2(accS[qt][kt][r]);
          accS[qt][kt][r] = e;
          ssum += e;
        }
      float2 sws = swap32(ssum);
      srun[qt] += sws.x + sws.y;
#pragma unroll
      for (int kt = 0; kt < 2; kt++)
#pragma unroll
        for (int s2 = 0; s2 < 2; s2++) {
          int f = kt * 2 + s2, rb = s2 * 8;
          unsigned u  = pkbf(accS[qt][kt][rb + 0], accS[qt][kt][rb + 1]);
          unsigned v2 = pkbf(accS[qt][kt][rb + 2], accS[qt][kt][rb + 3]);
          unsigned w2 = pkbf(accS[qt][kt][rb + 4], accS[qt][kt][rb + 5]);
          unsigned x2 = pkbf(accS[qt][kt][rb + 6], accS[qt][kt][rb + 7]);
          u32x2 r02 = __builtin_amdgcn_permlane32_swap(u, w2, false, false);
          u32x2 r13 = __builtin_amdgcn_permlane32_swap(v2, x2, false, false);
          pa[qt][f][0] = r02.x; pa[qt][f][1] = r13.x; pa[qt][f][2] = r02.y; pa[qt][f][3] = r13.y;
        }
    }

    // O accumulate
    __builtin_amdgcn_s_setprio(1);
#pragma unroll
    for (int f = 0; f < 4; f++)
#pragma unroll
      for (int qt = 0; qt < 2; qt++) {
        union { unsigned u[4]; bf16x8 v; } pf;
        pf.u[0] = pa[qt][f][0]; pf.u[1] = pa[qt][f][1];
        pf.u[2] = pa[qt][f][2]; pf.u[3] = pa[qt][f][3];
#pragma unroll
        for (int dh = 0; dh < 2; dh++)
          accO[qt][dh] = __builtin_amdgcn_mfma_f32_32x32x16_bf16(pf.v, vf[f * 2 + dh], accO[qt][dh], 0, 0, 0);
      }
    __builtin_amdgcn_s_setprio(0);
    __syncthreads();
    buf ^= 1;
  }

  // epilogue: per-q 1/sum via bpermute (q row cr lives in lane cr), bf16 stores
  __bf16* aobase = AO + (((size_t)b * 4096) << 10) + h * 64;
#pragma unroll
  for (int qt = 0; qt < 2; qt++) {
    float rinv = 1.0f / srun[qt];
    int ri = __float_as_int(rinv);
#pragma unroll
    for (int r = 0; r < 16; r++) {
      int cr = (r & 3) + ((r >> 2) << 3) + (hi << 2);
      float rv = __int_as_float(__builtin_amdgcn_ds_bpermute(cr << 2, ri));
      size_t rowoff = ((size_t)(q0 + w * 64 + qt * 32 + cr) << 10);
#pragma unroll
      for (int dh = 0; dh < 2; dh++)
        aobase[rowoff + dh * 32 + lq] = (__bf16)(accO[qt][dh][r] * rv);
    }
  }
}

extern "C" void kernel_launch(void* const* d_in, const int* in_sizes, int n_in,
                              void* d_out, int out_size, void* d_ws, size_t ws_size,
                              hipStream_t stream) {
  const float* img  = (const float*)d_in[0];
  const float* cnd  = (const float*)d_in[1];
  const float* qnw  = (const float*)d_in[2];
  const float* kvnw = (const float*)d_in[3];
  const float* qhw  = (const float*)d_in[4];
  const float* khw  = (const float*)d_in[5];
  const float* qw   = (const float*)d_in[6];
  const float* qb   = (const float*)d_in[7];
  const float* kw   = (const float*)d_in[8];
  const float* kb   = (const float*)d_in[9];
  const float* vw   = (const float*)d_in[10];
  const float* vb   = (const float*)d_in[11];
  const float* ow   = (const float*)d_in[12];
  const float* ob   = (const float*)d_in[13];
  const float* alpha= (const float*)d_in[14];
  const float* icos = (const float*)d_in[15];
  const float* isin = (const float*)d_in[16];
  const float* ccos = (const float*)d_in[17];
  const float* csin = (const float*)d_in[18];
  float* out = (float*)d_out;

  __bf16* p = (__bf16*)d_ws;
  __bf16* wqb = p; p += 1048576;
  __bf16* wkb = p; p += 1048576;   // wkb..wvb contiguous = (2048,1024) KV weight
  __bf16* wvb = p; p += 1048576;
  __bf16* wob = p; p += 1048576;
  __bf16* qn  = p; p += 8388608;   // (8192,1024); reused as AO after Q-GEMM consumes it
  __bf16* kvn = p; p += 2097152;
  __bf16* Qt  = p; p += 8388608;
  __bf16* Kt  = p; p += 2097152;
  __bf16* Vt0 = p; p += 2097152;
  __bf16* Kr  = p; p += 2097152;
  __bf16* Vtr = p; p += 2097152;
  __bf16* AO  = qn;  // qn dead after Q-GEMM

  rmsnorm2_kernel<<<10240, 256, 0, stream>>>(img, qnw, qn, 8192, cnd, kvnw, kvn);
  cast_w_kernel<<<2048, 256, 0, stream>>>(qw, kw, vw, ow, wqb, wkb, wvb, wob);

  gemm_bt_kernel<0><<<dim3(64, 8), 256, 0, stream>>>(qn, wqb, qb, Qt, nullptr, nullptr, nullptr, nullptr);
  gemm_bt_kernel<2><<<dim3(16, 16), 256, 0, stream>>>(kvn, wkb, kb, Kt, nullptr, nullptr, vb, Vt0);

  headnorm_rope_kernel<<<1024, 256, 0, stream>>>(Kt, khw, ccos, csin, Kr, 10, 1.0f);
  v_transpose_kernel<<<512, 256, 0, stream>>>(Vt0, Vtr);

  attn_kernel<<<dim3(16, 32), 256, 0, stream>>>(Qt, qhw, icos, isin, Kr, Vtr, AO);

  gemm_bt_kernel<1><<<dim3(64, 8), 256, 0, stream>>>(AO, wob, ob, out, img, alpha, nullptr, nullptr);
}

// Round 6
// 157.991 us; speedup vs baseline: 1.4629x; 1.0258x over previous
//
#include <hip/hip_runtime.h>

typedef __bf16 bf16x8 __attribute__((ext_vector_type(8)));
typedef __bf16 bf16x4 __attribute__((ext_vector_type(4)));
typedef float  f32x4  __attribute__((ext_vector_type(4)));
typedef float  f32x16 __attribute__((ext_vector_type(16)));
typedef unsigned u32x2 __attribute__((ext_vector_type(2)));

#define DEVINL __device__ __forceinline__

DEVINL void gload_lds16(const void* g, void* l) {
  __builtin_amdgcn_global_load_lds((const __attribute__((address_space(1))) void*)g,
                                   (__attribute__((address_space(3))) void*)l, 16, 0, 0);
}

DEVINL unsigned pkbf(float a, float b) {
  union { __bf16 h[2]; unsigned u; } c;
  c.h[0] = (__bf16)a; c.h[1] = (__bf16)b;
  return c.u;
}

// raw v_exp_f32 (exact for |x|<=12 domain; skips OCML fixup)
DEVINL float fast_exp2(float x) {
#if __has_builtin(__builtin_amdgcn_exp2f)
  return __builtin_amdgcn_exp2f(x);
#else
  float r;
  asm volatile("v_exp_f32 %0, %1" : "=v"(r) : "v"(x));
  return r;
#endif
}

// exchange lane halves: returns {x from lanes0-31 view, x from lanes32-63 view}
DEVINL float2 swap32(float x) {
  u32x2 r = __builtin_amdgcn_permlane32_swap(__float_as_uint(x), __float_as_uint(x), false, false);
  return make_float2(__uint_as_float(r.x), __uint_as_float(r.y));
}

// ---------------- prep: RMSNorm(img)+RMSNorm(cnd) + weight cast, one launch ----------------
__global__ __launch_bounds__(256) void prep_kernel(
    const float* __restrict__ XA, const float* __restrict__ WA, __bf16* __restrict__ YA,
    const float* __restrict__ XB, const float* __restrict__ WB, __bf16* __restrict__ YB,
    const float* __restrict__ wq, const float* __restrict__ wk,
    const float* __restrict__ wv, const float* __restrict__ wo,
    __bf16* __restrict__ oq, __bf16* __restrict__ ok,
    __bf16* __restrict__ ov, __bf16* __restrict__ oo) {
  int rb = blockIdx.x, tid = threadIdx.x;
  if (rb < 10240) {
    const float* X; const float* W; __bf16* Y; int row;
    if (rb < 8192) { X = XA; W = WA; Y = YA; row = rb; }
    else { X = XB; W = WB; Y = YB; row = rb - 8192; }
    const float4* xr = (const float4*)(X + (size_t)row * 1024);
    float4 v = xr[tid];
    float ss = v.x * v.x + v.y * v.y + v.z * v.z + v.w * v.w;
#pragma unroll
    for (int m = 1; m < 64; m <<= 1) ss += __shfl_xor(ss, m);
    __shared__ float part[4];
    if ((tid & 63) == 0) part[tid >> 6] = ss;
    __syncthreads();
    float tot = part[0] + part[1] + part[2] + part[3];
    float rn = rsqrtf(tot * (1.0f / 1024.0f) + 1e-6f);
    float4 wv4 = ((const float4*)W)[tid];
    bf16x4 y;
    y[0] = (__bf16)(v.x * rn * wv4.x);
    y[1] = (__bf16)(v.y * rn * wv4.y);
    y[2] = (__bf16)(v.z * rn * wv4.z);
    y[3] = (__bf16)(v.w * rn * wv4.w);
    *(bf16x4*)(Y + (size_t)row * 1024 + tid * 4) = y;
  } else {
    int gid = (rb - 10240) * 256 + tid;
    int which = gid >> 17;
    size_t off = (size_t)(gid & 131071) * 8;
    const float* s = (which == 0) ? wq : (which == 1) ? wk : (which == 2) ? wv : wo;
    __bf16* o = (which == 0) ? oq : (which == 1) ? ok : (which == 2) ? ov : oo;
    float4 v0 = *(const float4*)(s + off), v1 = *(const float4*)(s + off + 4);
    bf16x8 y;
    y[0] = (__bf16)v0.x; y[1] = (__bf16)v0.y; y[2] = (__bf16)v0.z; y[3] = (__bf16)v0.w;
    y[4] = (__bf16)v1.x; y[5] = (__bf16)v1.y; y[6] = (__bf16)v1.z; y[7] = (__bf16)v1.w;
    *(bf16x8*)(o + off) = y;
  }
}

// ---------------- merged Q + KV projection GEMM (768 blocks, all bf16-out) ----------------
// id<512: Qt = qn @ wq^T + qb (64x8 tiles). id>=512: K/V = kvn @ wkv^T + {kb,vb} (16x16).
__global__ __launch_bounds__(256) void qkv_gemm_kernel(
    const __bf16* __restrict__ qn, const __bf16* __restrict__ kvn,
    const __bf16* __restrict__ wq, const __bf16* __restrict__ wkv,
    const float* __restrict__ qb, const float* __restrict__ kb, const float* __restrict__ vb,
    __bf16* __restrict__ Qt, __bf16* __restrict__ Kt, __bf16* __restrict__ Vt0) {
  __shared__ __attribute__((aligned(16))) __bf16 As[128 * 32];
  __shared__ __attribute__((aligned(16))) __bf16 Bs[128 * 32];
  int id = blockIdx.x;
  const __bf16 *A, *Bw; const float* bias; __bf16* Cout;
  int m0, n0, nloc;
  if (id < 512) {
    A = qn; Bw = wq; m0 = (id & 63) * 128; n0 = (id >> 6) * 128; nloc = n0;
    bias = qb; Cout = Qt;
  } else {
    int i2 = id - 512;
    A = kvn; Bw = wkv; m0 = (i2 & 15) * 128; n0 = (i2 >> 4) * 128;
    if (n0 < 1024) { bias = kb; Cout = Kt; nloc = n0; }
    else { bias = vb; Cout = Vt0; nloc = n0 - 1024; }
  }
  int tid = threadIdx.x, lane = tid & 63, w = tid >> 6, wr = w >> 1, wc = w & 1;
  f32x4 z4 = {0.f, 0.f, 0.f, 0.f};
  f32x4 acc[4][4];
#pragma unroll
  for (int i = 0; i < 4; i++)
#pragma unroll
    for (int j = 0; j < 4; j++) acc[i][j] = z4;

  for (int k0 = 0; k0 < 1024; k0 += 32) {
#pragma unroll
    for (int i = 0; i < 2; i++) {
      int chunk = i * 256 + tid;
      int row = chunk >> 2, cc = chunk & 3;
      gload_lds16(A + (size_t)(m0 + row) * 1024 + k0 + cc * 8, (char*)As + i * 4096 + w * 1024);
      gload_lds16(Bw + (size_t)(n0 + row) * 1024 + k0 + cc * 8, (char*)Bs + i * 4096 + w * 1024);
    }
    __syncthreads();
    bf16x8 af[4], bfr[4];
#pragma unroll
    for (int m = 0; m < 4; m++) {
      int r = wr * 64 + m * 16 + (lane & 15);
      af[m] = *(const bf16x8*)((const char*)As + r * 64 + ((lane >> 4) << 4));
    }
#pragma unroll
    for (int n = 0; n < 4; n++) {
      int r = wc * 64 + n * 16 + (lane & 15);
      bfr[n] = *(const bf16x8*)((const char*)Bs + r * 64 + ((lane >> 4) << 4));
    }
#pragma unroll
    for (int m = 0; m < 4; m++)
#pragma unroll
      for (int n = 0; n < 4; n++)
        acc[m][n] = __builtin_amdgcn_mfma_f32_16x16x32_bf16(af[m], bfr[n], acc[m][n], 0, 0, 0);
    __syncthreads();
  }

#pragma unroll
  for (int m = 0; m < 4; m++)
#pragma unroll
    for (int n = 0; n < 4; n++) {
      int col = nloc + wc * 64 + n * 16 + (lane & 15);
      float bv = bias[col];
#pragma unroll
      for (int r = 0; r < 4; r++) {
        int row = m0 + wr * 64 + m * 16 + ((lane >> 4) << 2) + r;
        size_t idx = ((size_t)row << 10) + col;
        Cout[idx] = (__bf16)(acc[m][n][r] + bv);
      }
    }
}

// ---------------- O-projection GEMM with residual epilogue ----------------
__global__ __launch_bounds__(256) void gemm_o_kernel(
    const __bf16* __restrict__ A, const __bf16* __restrict__ Bw,
    const float* __restrict__ bias, float* __restrict__ Cout,
    const float* __restrict__ resid, const float* __restrict__ alphap) {
  __shared__ __attribute__((aligned(16))) __bf16 As[128 * 32];
  __shared__ __attribute__((aligned(16))) __bf16 Bs[128 * 32];
  int tid = threadIdx.x, lane = tid & 63, w = tid >> 6, wr = w >> 1, wc = w & 1;
  int m0 = blockIdx.x * 128, n0 = blockIdx.y * 128;
  f32x4 z4 = {0.f, 0.f, 0.f, 0.f};
  f32x4 acc[4][4];
#pragma unroll
  for (int i = 0; i < 4; i++)
#pragma unroll
    for (int j = 0; j < 4; j++) acc[i][j] = z4;

  for (int k0 = 0; k0 < 1024; k0 += 32) {
#pragma unroll
    for (int i = 0; i < 2; i++) {
      int chunk = i * 256 + tid;
      int row = chunk >> 2, cc = chunk & 3;
      gload_lds16(A + (size_t)(m0 + row) * 1024 + k0 + cc * 8, (char*)As + i * 4096 + w * 1024);
      gload_lds16(Bw + (size_t)(n0 + row) * 1024 + k0 + cc * 8, (char*)Bs + i * 4096 + w * 1024);
    }
    __syncthreads();
    bf16x8 af[4], bfr[4];
#pragma unroll
    for (int m = 0; m < 4; m++) {
      int r = wr * 64 + m * 16 + (lane & 15);
      af[m] = *(const bf16x8*)((const char*)As + r * 64 + ((lane >> 4) << 4));
    }
#pragma unroll
    for (int n = 0; n < 4; n++) {
      int r = wc * 64 + n * 16 + (lane & 15);
      bfr[n] = *(const bf16x8*)((const char*)Bs + r * 64 + ((lane >> 4) << 4));
    }
#pragma unroll
    for (int m = 0; m < 4; m++)
#pragma unroll
      for (int n = 0; n < 4; n++)
        acc[m][n] = __builtin_amdgcn_mfma_f32_16x16x32_bf16(af[m], bfr[n], acc[m][n], 0, 0, 0);
    __syncthreads();
  }

  float aval = alphap[0];
#pragma unroll
  for (int m = 0; m < 4; m++)
#pragma unroll
    for (int n = 0; n < 4; n++) {
      int col = n0 + wc * 64 + n * 16 + (lane & 15);
      float bv = bias[col];
#pragma unroll
      for (int r = 0; r < 4; r++) {
        int row = m0 + wr * 64 + m * 16 + ((lane >> 4) << 2) + r;
        size_t idx = ((size_t)row << 10) + col;
        Cout[idx] = resid[idx] + aval * (acc[m][n][r] + bv);
      }
    }
}

// ---------------- kprep: K head-RMSNorm+RoPE ∪ V transpose, one launch ----------------
__global__ __launch_bounds__(256) void kprep_kernel(
    const __bf16* __restrict__ Kt, const float* __restrict__ KHW,
    const float* __restrict__ CCOS, const float* __restrict__ CSIN,
    __bf16* __restrict__ Kr,
    const __bf16* __restrict__ V, __bf16* __restrict__ Vt) {
  int rb = blockIdx.x, tid = threadIdx.x;
  if (rb < 1024) {
    // K head-norm + RoPE: 2048 tokens x 16 heads, 8 lanes per (token,head)
    int inst = rb * 32 + (tid >> 3);
    int sub = tid & 7;
    int token = inst >> 4, h = inst & 15;
    int b = token >> 10, pos = token & 1023;
    const __bf16* xp = Kt + ((size_t)token << 10) + h * 64 + sub * 8;
    bf16x8 xv = *(const bf16x8*)xp;
    float xf[8];
#pragma unroll
    for (int i = 0; i < 8; i++) xf[i] = (float)xv[i];
    float ss = 0.f;
#pragma unroll
    for (int i = 0; i < 8; i++) ss += xf[i] * xf[i];
    ss += __shfl_xor(ss, 1);
    ss += __shfl_xor(ss, 2);
    ss += __shfl_xor(ss, 4);
    float rn = rsqrtf(ss * (1.0f / 64.0f) + 1e-6f);
    const float* hwp = KHW + sub * 8;
    const float* cp = CCOS + ((size_t)pos << 6) + sub * 8;
    const float* sp = CSIN + ((size_t)pos << 6) + sub * 8;
    float xn[8], o[8];
#pragma unroll
    for (int i = 0; i < 8; i++) xn[i] = xf[i] * rn * hwp[i];
#pragma unroll
    for (int i = 0; i < 8; i += 2) {
      o[i] = xn[i] * cp[i] - xn[i + 1] * sp[i];
      o[i + 1] = xn[i + 1] * cp[i + 1] + xn[i] * sp[i + 1];
    }
    bf16x8 yv;
#pragma unroll
    for (int i = 0; i < 8; i++) yv[i] = (__bf16)o[i];
    *(bf16x8*)(Kr + (((size_t)((b << 4) + h) << 10) + pos) * 64 + sub * 8) = yv;
  } else {
    // V transpose: (B*1024,1024) token-major -> (B,16,64,1024)
    int bx = rb - 1024;
    int bh = bx >> 4;
    int j0 = (bx & 15) * 64;
    int b = bh >> 4, h = bh & 15;
#pragma unroll
    for (int it = 0; it < 2; ++it) {
      int c = it * 256 + tid;
      int jl = c >> 3, d0 = (c & 7) * 8;
      bf16x8 v = *(const bf16x8*)(V + (size_t)(b * 1024 + j0 + jl) * 1024 + h * 64 + d0);
#pragma unroll
      for (int i = 0; i < 8; i++)
        Vt[((size_t)bh * 64 + d0 + i) * 1024 + j0 + jl] = v[i];
    }
  }
}

// ---------------- flash attention: 3-buffer counted-vmcnt pipeline, 64q/wave ----------------
// Qt: (B*4096,1024) bf16 ; Kr: (B,16,1024,64) ; Vtr: (B,16,64,1024) ; AO: (B*4096,1024).
// 4 waves/block, wave owns 64 q (2 subtiles of 32; lane&31=q). Fragment-linear LDS
// (8 slots x 1KB per K/V tile): zero bank conflicts. 2-tile-ahead prefetch with raw
// s_barrier + counted s_waitcnt vmcnt(4) (T4) -- never drains the pipeline.
// P = exp2(S) directly (head-RMSNorm bounds |S|<=11.6). XCD swizzle: 4 heads/XCD.
__global__ __launch_bounds__(256, 2) void attn_kernel(
    const __bf16* __restrict__ Qt, const float* __restrict__ QHW,
    const float* __restrict__ QCOS, const float* __restrict__ QSIN,
    const __bf16* __restrict__ Kr, const __bf16* __restrict__ Vtr,
    __bf16* __restrict__ AO) {
  int tid = threadIdx.x, lane = tid & 63, w = tid >> 6;
  int lq = lane & 31, hi = lane >> 5;
  // XCD-aware swizzle (512 blocks, 8 XCDs, 64 blocks/XCD -> 4 heads per XCD)
  int wgid = blockIdx.x;
  int nid = (wgid & 7) * 64 + (wgid >> 3);
  int q0 = (nid & 15) * 256;
  int bh = nid >> 4, b = bh >> 4, h = bh & 15;
  const float QSC = 0.125f * 1.44269504088896340736f;  // 1/sqrt(64) * log2(e)

  __shared__ __attribute__((aligned(16))) __bf16 Ks[3][4096];
  __shared__ __attribute__((aligned(16))) __bf16 Vs[3][4096];

  const __bf16* Kbh = Kr + ((size_t)bh << 16);
  const __bf16* Vbh = Vtr + ((size_t)bh << 16);

  auto STAGE = [&](int T, int BSEL) {
#pragma unroll
    for (int i = 0; i < 2; i++) {
      int s = 2 * w + i;
      int kt = s >> 2, ds2 = s & 3;
      gload_lds16(Kbh + (size_t)(T * 64 + kt * 32 + lq) * 64 + ds2 * 16 + hi * 8,
                  (char*)Ks[BSEL] + s * 1024);
      int f = s >> 1, dh = s & 1;
      gload_lds16(Vbh + (size_t)(dh * 32 + lq) * 1024 + T * 64 + f * 16 + hi * 8,
                  (char*)Vs[BSEL] + s * 1024);
    }
  };

  STAGE(0, 0);
  STAGE(1, 1);

  // ---- fused Q head-RMSNorm + RoPE + scale (overlaps tile-0/1 staging)
  bf16x8 qf[2][4];
#pragma unroll
  for (int qt = 0; qt < 2; qt++) {
    int pos = q0 + w * 64 + qt * 32 + lq;
    const __bf16* qp = Qt + ((size_t)(b * 4096 + pos) << 10) + h * 64 + hi * 8;
    float xf[4][8];
    float ss = 0.f;
#pragma unroll
    for (int ds = 0; ds < 4; ds++) {
      bf16x8 xv = *(const bf16x8*)(qp + ds * 16);
#pragma unroll
      for (int j = 0; j < 8; j++) { float f = (float)xv[j]; xf[ds][j] = f; ss += f * f; }
    }
    float2 sw = swap32(ss);
    float rn = rsqrtf((sw.x + sw.y) * (1.0f / 64.0f) + 1e-6f);
#pragma unroll
    for (int ds = 0; ds < 4; ds++) {
      int d0 = ds * 16 + hi * 8;
      const float* wp = QHW + d0;
      const float* cp = QCOS + ((size_t)pos << 6) + d0;
      const float* sp = QSIN + ((size_t)pos << 6) + d0;
      float4 wa = *(const float4*)wp, wb = *(const float4*)(wp + 4);
      float4 ca = *(const float4*)cp, cb = *(const float4*)(cp + 4);
      float4 sa = *(const float4*)sp, sb = *(const float4*)(sp + 4);
      float wv[8] = {wa.x, wa.y, wa.z, wa.w, wb.x, wb.y, wb.z, wb.w};
      float cv[8] = {ca.x, ca.y, ca.z, ca.w, cb.x, cb.y, cb.z, cb.w};
      float sv[8] = {sa.x, sa.y, sa.z, sa.w, sb.x, sb.y, sb.z, sb.w};
      float xn[8];
#pragma unroll
      for (int j = 0; j < 8; j++) xn[j] = xf[ds][j] * rn * wv[j];
      bf16x8 q8;
#pragma unroll
      for (int j = 0; j < 8; j += 2) {
        q8[j]     = (__bf16)((xn[j] * cv[j] - xn[j + 1] * sv[j]) * QSC);
        q8[j + 1] = (__bf16)((xn[j + 1] * cv[j + 1] + xn[j] * sv[j + 1]) * QSC);
      }
      qf[qt][ds] = q8;
    }
  }

  f32x16 Z16;
#pragma unroll
  for (int r = 0; r < 16; r++) Z16[r] = 0.f;
  f32x16 accO[2][2];
#pragma unroll
  for (int qt = 0; qt < 2; qt++)
#pragma unroll
    for (int dh = 0; dh < 2; dh++) accO[qt][dh] = Z16;
  float srun[2] = {0.f, 0.f};

  // tile 0 ready (tile 1's 4 loads may stay in flight)
  asm volatile("s_waitcnt vmcnt(4)" ::: "memory");
  __builtin_amdgcn_s_barrier();
  asm volatile("" ::: "memory");

  int cur = 0, stg = 2;
  for (int t = 0; t < 16; t++) {
    if (t < 14) STAGE(t + 2, stg);
    const char* kbase = (const char*)Ks[cur];
    const char* vbase = (const char*)Vs[cur];
    int loff = lane * 16;

    bf16x8 kf[8], vf[8];
#pragma unroll
    for (int s = 0; s < 8; s++) kf[s] = *(const bf16x8*)(kbase + s * 1024 + loff);
#pragma unroll
    for (int s = 0; s < 8; s++) vf[s] = *(const bf16x8*)(vbase + s * 1024 + loff);

    // S^T = K Q^T per q-subtile (first MFMA consumes Z16)
    f32x16 accS[2][2];
    __builtin_amdgcn_s_setprio(1);
#pragma unroll
    for (int qt = 0; qt < 2; qt++)
#pragma unroll
      for (int kt = 0; kt < 2; kt++) {
        accS[qt][kt] = __builtin_amdgcn_mfma_f32_32x32x16_bf16(kf[kt * 4], qf[qt][0], Z16, 0, 0, 0);
#pragma unroll
        for (int ds = 1; ds < 4; ds++)
          accS[qt][kt] = __builtin_amdgcn_mfma_f32_32x32x16_bf16(kf[kt * 4 + ds], qf[qt][ds], accS[qt][kt], 0, 0, 0);
      }
    __builtin_amdgcn_s_setprio(0);

    // P = exp2(S), row-sums, pack to A-frags (permlane32_swap half-exchange)
    unsigned pa[2][4][4];
#pragma unroll
    for (int qt = 0; qt < 2; qt++) {
      float ssum = 0.f;
#pragma unroll
      for (int kt = 0; kt < 2; kt++)
#pragma unroll
        for (int r = 0; r < 16; r++) {
          float e = fast_exp2(accS[qt][kt][r]);
          accS[qt][kt][r] = e;
          ssum += e;
        }
      float2 sws = swap32(ssum);
      srun[qt] += sws.x + sws.y;
#pragma unroll
      for (int kt = 0; kt < 2; kt++)
#pragma unroll
        for (int s2 = 0; s2 < 2; s2++) {
          int f = kt * 2 + s2, rb = s2 * 8;
          unsigned u  = pkbf(accS[qt][kt][rb + 0], accS[qt][kt][rb + 1]);
          unsigned v2 = pkbf(accS[qt][kt][rb + 2], accS[qt][kt][rb + 3]);
          unsigned w2 = pkbf(accS[qt][kt][rb + 4], accS[qt][kt][rb + 5]);
          unsigned x2 = pkbf(accS[qt][kt][rb + 6], accS[qt][kt][rb + 7]);
          u32x2 r02 = __builtin_amdgcn_permlane32_swap(u, w2, false, false);
          u32x2 r13 = __builtin_amdgcn_permlane32_swap(v2, x2, false, false);
          pa[qt][f][0] = r02.x; pa[qt][f][1] = r13.x; pa[qt][f][2] = r02.y; pa[qt][f][3] = r13.y;
        }
    }

    // O accumulate
    __builtin_amdgcn_s_setprio(1);
#pragma unroll
    for (int f = 0; f < 4; f++)
#pragma unroll
      for (int qt = 0; qt < 2; qt++) {
        union { unsigned u[4]; bf16x8 v; } pf;
        pf.u[0] = pa[qt][f][0]; pf.u[1] = pa[qt][f][1];
        pf.u[2] = pa[qt][f][2]; pf.u[3] = pa[qt][f][3];
#pragma unroll
        for (int dh = 0; dh < 2; dh++)
          accO[qt][dh] = __builtin_amdgcn_mfma_f32_32x32x16_bf16(pf.v, vf[f * 2 + dh], accO[qt][dh], 0, 0, 0);
      }
    __builtin_amdgcn_s_setprio(0);

    // counted wait: only tile t+1's loads must be resident; t+2's stay in flight
    if (t < 14) {
      asm volatile("s_waitcnt vmcnt(4)" ::: "memory");
      __builtin_amdgcn_s_barrier();
      asm volatile("" ::: "memory");
    } else if (t == 14) {
      asm volatile("s_waitcnt vmcnt(0)" ::: "memory");
      __builtin_amdgcn_s_barrier();
      asm volatile("" ::: "memory");
    }
    cur = (cur == 2) ? 0 : cur + 1;
    stg = (stg == 2) ? 0 : stg + 1;
  }

  // epilogue: per-q 1/sum via bpermute (q row cr lives in lane cr), bf16 stores
  __bf16* aobase = AO + (((size_t)b * 4096) << 10) + h * 64;
#pragma unroll
  for (int qt = 0; qt < 2; qt++) {
    float rinv = 1.0f / srun[qt];
    int ri = __float_as_int(rinv);
#pragma unroll
    for (int r = 0; r < 16; r++) {
      int cr = (r & 3) + ((r >> 2) << 3) + (hi << 2);
      float rv = __int_as_float(__builtin_amdgcn_ds_bpermute(cr << 2, ri));
      size_t rowoff = ((size_t)(q0 + w * 64 + qt * 32 + cr) << 10);
#pragma unroll
      for (int dh = 0; dh < 2; dh++)
        aobase[rowoff + dh * 32 + lq] = (__bf16)(accO[qt][dh][r] * rv);
    }
  }
}

extern "C" void kernel_launch(void* const* d_in, const int* in_sizes, int n_in,
                              void* d_out, int out_size, void* d_ws, size_t ws_size,
                              hipStream_t stream) {
  const float* img  = (const float*)d_in[0];
  const float* cnd  = (const float*)d_in[1];
  const float* qnw  = (const float*)d_in[2];
  const float* kvnw = (const float*)d_in[3];
  const float* qhw  = (const float*)d_in[4];
  const float* khw  = (const float*)d_in[5];
  const float* qw   = (const float*)d_in[6];
  const float* qb   = (const float*)d_in[7];
  const float* kw   = (const float*)d_in[8];
  const float* kb   = (const float*)d_in[9];
  const float* vw   = (const float*)d_in[10];
  const float* vb   = (const float*)d_in[11];
  const float* ow   = (const float*)d_in[12];
  const float* ob   = (const float*)d_in[13];
  const float* alpha= (const float*)d_in[14];
  const float* icos = (const float*)d_in[15];
  const float* isin = (const float*)d_in[16];
  const float* ccos = (const float*)d_in[17];
  const float* csin = (const float*)d_in[18];
  float* out = (float*)d_out;

  __bf16* p = (__bf16*)d_ws;
  __bf16* wqb = p; p += 1048576;
  __bf16* wkb = p; p += 1048576;   // wkb..wvb contiguous = (2048,1024) KV weight
  __bf16* wvb = p; p += 1048576;
  __bf16* wob = p; p += 1048576;
  __bf16* qn  = p; p += 8388608;   // (8192,1024); reused as AO after Q-GEMM consumes it
  __bf16* kvn = p; p += 2097152;
  __bf16* Qt  = p; p += 8388608;
  __bf16* Kt  = p; p += 2097152;
  __bf16* Vt0 = p; p += 2097152;
  __bf16* Kr  = p; p += 2097152;
  __bf16* Vtr = p; p += 2097152;
  __bf16* AO  = qn;  // qn dead after Q-GEMM

  prep_kernel<<<12288, 256, 0, stream>>>(img, qnw, qn, cnd, kvnw, kvn,
                                         qw, kw, vw, ow, wqb, wkb, wvb, wob);

  qkv_gemm_kernel<<<768, 256, 0, stream>>>(qn, kvn, wqb, wkb, qb, kb, vb, Qt, Kt, Vt0);

  kprep_kernel<<<1536, 256, 0, stream>>>(Kt, khw, ccos, csin, Kr, Vt0, Vtr);

  attn_kernel<<<512, 256, 0, stream>>>(Qt, qhw, icos, isin, Kr, Vtr, AO);

  gemm_o_kernel<<<dim3(64, 8), 256, 0, stream>>>(AO, wob, ob, out, img, alpha);
}

// Round 7
// 151.979 us; speedup vs baseline: 1.5208x; 1.0396x over previous
//
#include <hip/hip_runtime.h>

typedef __bf16 bf16x8 __attribute__((ext_vector_type(8)));
typedef __bf16 bf16x4 __attribute__((ext_vector_type(4)));
typedef float  f32x4  __attribute__((ext_vector_type(4)));
typedef float  f32x16 __attribute__((ext_vector_type(16)));
typedef unsigned u32x2 __attribute__((ext_vector_type(2)));

#define DEVINL __device__ __forceinline__

DEVINL void gload_lds16(const void* g, void* l) {
  __builtin_amdgcn_global_load_lds((const __attribute__((address_space(1))) void*)g,
                                   (__attribute__((address_space(3))) void*)l, 16, 0, 0);
}

DEVINL unsigned pkbf(float a, float b) {
  union { __bf16 h[2]; unsigned u; } c;
  c.h[0] = (__bf16)a; c.h[1] = (__bf16)b;
  return c.u;
}

// raw v_exp_f32 (exact for |x|<=12 domain; skips OCML fixup)
DEVINL float fast_exp2(float x) {
#if __has_builtin(__builtin_amdgcn_exp2f)
  return __builtin_amdgcn_exp2f(x);
#else
  float r;
  asm volatile("v_exp_f32 %0, %1" : "=v"(r) : "v"(x));
  return r;
#endif
}

// exchange lane halves: returns {x from lanes0-31 view, x from lanes32-63 view}
DEVINL float2 swap32(float x) {
  u32x2 r = __builtin_amdgcn_permlane32_swap(__float_as_uint(x), __float_as_uint(x), false, false);
  return make_float2(__uint_as_float(r.x), __uint_as_float(r.y));
}

// ---------------- prep: RMSNorm(img)+RMSNorm(cnd) + weight cast, one launch ----------------
__global__ __launch_bounds__(256) void prep_kernel(
    const float* __restrict__ XA, const float* __restrict__ WA, __bf16* __restrict__ YA,
    const float* __restrict__ XB, const float* __restrict__ WB, __bf16* __restrict__ YB,
    const float* __restrict__ wq, const float* __restrict__ wk,
    const float* __restrict__ wv, const float* __restrict__ wo,
    __bf16* __restrict__ oq, __bf16* __restrict__ ok,
    __bf16* __restrict__ ov, __bf16* __restrict__ oo) {
  int rb = blockIdx.x, tid = threadIdx.x;
  if (rb < 10240) {
    const float* X; const float* W; __bf16* Y; int row;
    if (rb < 8192) { X = XA; W = WA; Y = YA; row = rb; }
    else { X = XB; W = WB; Y = YB; row = rb - 8192; }
    const float4* xr = (const float4*)(X + (size_t)row * 1024);
    float4 v = xr[tid];
    float ss = v.x * v.x + v.y * v.y + v.z * v.z + v.w * v.w;
#pragma unroll
    for (int m = 1; m < 64; m <<= 1) ss += __shfl_xor(ss, m);
    __shared__ float part[4];
    if ((tid & 63) == 0) part[tid >> 6] = ss;
    __syncthreads();
    float tot = part[0] + part[1] + part[2] + part[3];
    float rn = rsqrtf(tot * (1.0f / 1024.0f) + 1e-6f);
    float4 wv4 = ((const float4*)W)[tid];
    bf16x4 y;
    y[0] = (__bf16)(v.x * rn * wv4.x);
    y[1] = (__bf16)(v.y * rn * wv4.y);
    y[2] = (__bf16)(v.z * rn * wv4.z);
    y[3] = (__bf16)(v.w * rn * wv4.w);
    *(bf16x4*)(Y + (size_t)row * 1024 + tid * 4) = y;
  } else {
    int gid = (rb - 10240) * 256 + tid;
    int which = gid >> 17;
    size_t off = (size_t)(gid & 131071) * 8;
    const float* s = (which == 0) ? wq : (which == 1) ? wk : (which == 2) ? wv : wo;
    __bf16* o = (which == 0) ? oq : (which == 1) ? ok : (which == 2) ? ov : oo;
    float4 v0 = *(const float4*)(s + off), v1 = *(const float4*)(s + off + 4);
    bf16x8 y;
    y[0] = (__bf16)v0.x; y[1] = (__bf16)v0.y; y[2] = (__bf16)v0.z; y[3] = (__bf16)v0.w;
    y[4] = (__bf16)v1.x; y[5] = (__bf16)v1.y; y[6] = (__bf16)v1.z; y[7] = (__bf16)v1.w;
    *(bf16x8*)(o + off) = y;
  }
}

// ---------------- GEMM core: double-buffered, 1-ahead prefetch, counted vmcnt ----------------
// A (M,1024), Bw rows n0.., 32 K-steps. acc 4x4 f32x4 per thread (128x128 tile, 4 waves).
template <typename EPIF>
DEVINL void gemm_core(const __bf16* __restrict__ A, const __bf16* __restrict__ Bw,
                      int m0, int n0, char* AsB, char* BsB, EPIF epi) {
  int tid = threadIdx.x, lane = tid & 63, w = tid >> 6, wr = w >> 1, wc = w & 1;
  f32x4 z4 = {0.f, 0.f, 0.f, 0.f};
  f32x4 acc[4][4];
#pragma unroll
  for (int i = 0; i < 4; i++)
#pragma unroll
    for (int j = 0; j < 4; j++) acc[i][j] = z4;

  auto STAGE = [&](int k0, int bsel) {
#pragma unroll
    for (int i = 0; i < 2; i++) {
      int chunk = i * 256 + tid;
      int row = chunk >> 2, cc = chunk & 3;
      gload_lds16(A + (size_t)(m0 + row) * 1024 + k0 + cc * 8,
                  AsB + bsel * 8192 + i * 4096 + w * 1024);
      gload_lds16(Bw + (size_t)(n0 + row) * 1024 + k0 + cc * 8,
                  BsB + bsel * 8192 + i * 4096 + w * 1024);
    }
  };

  STAGE(0, 0);
  int b = 0;
  for (int it = 0; it < 32; ++it) {
    if (it < 31) {
      STAGE((it + 1) * 32, b ^ 1);
      asm volatile("s_waitcnt vmcnt(4)" ::: "memory");
    } else {
      asm volatile("s_waitcnt vmcnt(0)" ::: "memory");
    }
    __builtin_amdgcn_s_barrier();
    asm volatile("" ::: "memory");
    const char* As = AsB + b * 8192;
    const char* Bs = BsB + b * 8192;
    bf16x8 af[4], bfr[4];
#pragma unroll
    for (int m = 0; m < 4; m++) {
      int r = wr * 64 + m * 16 + (lane & 15);
      af[m] = *(const bf16x8*)(As + r * 64 + ((lane >> 4) << 4));
    }
#pragma unroll
    for (int n = 0; n < 4; n++) {
      int r = wc * 64 + n * 16 + (lane & 15);
      bfr[n] = *(const bf16x8*)(Bs + r * 64 + ((lane >> 4) << 4));
    }
    __builtin_amdgcn_s_setprio(1);
#pragma unroll
    for (int m = 0; m < 4; m++)
#pragma unroll
      for (int n = 0; n < 4; n++)
        acc[m][n] = __builtin_amdgcn_mfma_f32_16x16x32_bf16(af[m], bfr[n], acc[m][n], 0, 0, 0);
    __builtin_amdgcn_s_setprio(0);
    __builtin_amdgcn_s_barrier();
    asm volatile("" ::: "memory");
    b ^= 1;
  }
  epi(acc, lane, wr, wc);
}

// ---------------- merged Q + KV projection GEMM (768 blocks, all bf16-out) ----------------
__global__ __launch_bounds__(256) void qkv_gemm_kernel(
    const __bf16* __restrict__ qn, const __bf16* __restrict__ kvn,
    const __bf16* __restrict__ wq, const __bf16* __restrict__ wkv,
    const float* __restrict__ qb, const float* __restrict__ kb, const float* __restrict__ vb,
    __bf16* __restrict__ Qt, __bf16* __restrict__ Kt, __bf16* __restrict__ Vt0) {
  __shared__ __attribute__((aligned(16))) char AsB[2 * 8192];
  __shared__ __attribute__((aligned(16))) char BsB[2 * 8192];
  int id = blockIdx.x;
  const __bf16 *A, *Bw; const float* bias; __bf16* Cout;
  int m0, n0, nloc;
  if (id < 512) {
    A = qn; Bw = wq; m0 = (id & 63) * 128; n0 = (id >> 6) * 128; nloc = n0;
    bias = qb; Cout = Qt;
  } else {
    int i2 = id - 512;
    A = kvn; Bw = wkv; m0 = (i2 & 15) * 128; n0 = (i2 >> 4) * 128;
    if (n0 < 1024) { bias = kb; Cout = Kt; nloc = n0; }
    else { bias = vb; Cout = Vt0; nloc = n0 - 1024; }
  }
  gemm_core(A, Bw, m0, n0, AsB, BsB,
            [&](f32x4 (&acc)[4][4], int lane, int wr, int wc) {
#pragma unroll
              for (int m = 0; m < 4; m++)
#pragma unroll
                for (int n = 0; n < 4; n++) {
                  int col = nloc + wc * 64 + n * 16 + (lane & 15);
                  float bv = bias[col];
#pragma unroll
                  for (int r = 0; r < 4; r++) {
                    int row = m0 + wr * 64 + m * 16 + ((lane >> 4) << 2) + r;
                    Cout[((size_t)row << 10) + col] = (__bf16)(acc[m][n][r] + bv);
                  }
                }
            });
}

// ---------------- O-projection GEMM with residual epilogue ----------------
__global__ __launch_bounds__(256) void gemm_o_kernel(
    const __bf16* __restrict__ A, const __bf16* __restrict__ Bw,
    const float* __restrict__ bias, float* __restrict__ Cout,
    const float* __restrict__ resid, const float* __restrict__ alphap) {
  __shared__ __attribute__((aligned(16))) char AsB[2 * 8192];
  __shared__ __attribute__((aligned(16))) char BsB[2 * 8192];
  int m0 = blockIdx.x * 128, n0 = blockIdx.y * 128;
  float aval = alphap[0];
  gemm_core(A, Bw, m0, n0, AsB, BsB,
            [&](f32x4 (&acc)[4][4], int lane, int wr, int wc) {
#pragma unroll
              for (int m = 0; m < 4; m++)
#pragma unroll
                for (int n = 0; n < 4; n++) {
                  int col = n0 + wc * 64 + n * 16 + (lane & 15);
                  float bv = bias[col];
#pragma unroll
                  for (int r = 0; r < 4; r++) {
                    int row = m0 + wr * 64 + m * 16 + ((lane >> 4) << 2) + r;
                    size_t idx = ((size_t)row << 10) + col;
                    Cout[idx] = resid[idx] + aval * (acc[m][n][r] + bv);
                  }
                }
            });
}

// ---------------- kprep: K head-RMSNorm+RoPE ∪ V transpose, one launch ----------------
__global__ __launch_bounds__(256) void kprep_kernel(
    const __bf16* __restrict__ Kt, const float* __restrict__ KHW,
    const float* __restrict__ CCOS, const float* __restrict__ CSIN,
    __bf16* __restrict__ Kr,
    const __bf16* __restrict__ V, __bf16* __restrict__ Vt) {
  int rb = blockIdx.x, tid = threadIdx.x;
  if (rb < 1024) {
    int inst = rb * 32 + (tid >> 3);
    int sub = tid & 7;
    int token = inst >> 4, h = inst & 15;
    int b = token >> 10, pos = token & 1023;
    const __bf16* xp = Kt + ((size_t)token << 10) + h * 64 + sub * 8;
    bf16x8 xv = *(const bf16x8*)xp;
    float xf[8];
#pragma unroll
    for (int i = 0; i < 8; i++) xf[i] = (float)xv[i];
    float ss = 0.f;
#pragma unroll
    for (int i = 0; i < 8; i++) ss += xf[i] * xf[i];
    ss += __shfl_xor(ss, 1);
    ss += __shfl_xor(ss, 2);
    ss += __shfl_xor(ss, 4);
    float rn = rsqrtf(ss * (1.0f / 64.0f) + 1e-6f);
    const float* hwp = KHW + sub * 8;
    const float* cp = CCOS + ((size_t)pos << 6) + sub * 8;
    const float* sp = CSIN + ((size_t)pos << 6) + sub * 8;
    float xn[8], o[8];
#pragma unroll
    for (int i = 0; i < 8; i++) xn[i] = xf[i] * rn * hwp[i];
#pragma unroll
    for (int i = 0; i < 8; i += 2) {
      o[i] = xn[i] * cp[i] - xn[i + 1] * sp[i];
      o[i + 1] = xn[i + 1] * cp[i + 1] + xn[i] * sp[i + 1];
    }
    bf16x8 yv;
#pragma unroll
    for (int i = 0; i < 8; i++) yv[i] = (__bf16)o[i];
    *(bf16x8*)(Kr + (((size_t)((b << 4) + h) << 10) + pos) * 64 + sub * 8) = yv;
  } else {
    int bx = rb - 1024;
    int bh = bx >> 4;
    int j0 = (bx & 15) * 64;
    int b = bh >> 4, h = bh & 15;
#pragma unroll
    for (int it = 0; it < 2; ++it) {
      int c = it * 256 + tid;
      int jl = c >> 3, d0 = (c & 7) * 8;
      bf16x8 v = *(const bf16x8*)(V + (size_t)(b * 1024 + j0 + jl) * 1024 + h * 64 + d0);
#pragma unroll
      for (int i = 0; i < 8; i++)
        Vt[((size_t)bh * 64 + d0 + i) * 1024 + j0 + jl] = v[i];
    }
  }
}

// ---------------- flash attention: 128q/block, 32q/wave, 2-buffer counted-vmcnt ----------------
// Qt: (B*4096,1024) bf16 ; Kr: (B,16,1024,64) ; Vtr: (B,16,64,1024) ; AO: (B*4096,1024).
// 4 waves/block, each wave one 32-q subtile (lane&31=q). Fragment-linear LDS (8 slots
// x 1KB per K/V tile), zero conflicts. 1-ahead prefetch, vmcnt(4), raw barriers.
// P = exp2(S) directly (head-RMSNorm bounds |S|<=11.6). XCD swizzle: 4 heads/XCD.
__global__ __launch_bounds__(256, 3) void attn_kernel(
    const __bf16* __restrict__ Qt, const float* __restrict__ QHW,
    const float* __restrict__ QCOS, const float* __restrict__ QSIN,
    const __bf16* __restrict__ Kr, const __bf16* __restrict__ Vtr,
    __bf16* __restrict__ AO) {
  int tid = threadIdx.x, lane = tid & 63, w = tid >> 6;
  int lq = lane & 31, hi = lane >> 5;
  // XCD-aware swizzle (1024 blocks, 8 XCDs, 128 blocks/XCD -> 4 heads per XCD)
  int wgid = blockIdx.x;
  int nid = (wgid & 7) * 128 + (wgid >> 3);
  int q0 = (nid & 31) * 128;
  int bh = nid >> 5, b = bh >> 4, h = bh & 15;
  const float QSC = 0.125f * 1.44269504088896340736f;  // 1/sqrt(64) * log2(e)

  __shared__ __attribute__((aligned(16))) __bf16 Ks[2][4096];
  __shared__ __attribute__((aligned(16))) __bf16 Vs[2][4096];

  const __bf16* Kbh = Kr + ((size_t)bh << 16);
  const __bf16* Vbh = Vtr + ((size_t)bh << 16);

  auto STAGE = [&](int T, int BSEL) {
#pragma unroll
    for (int i = 0; i < 2; i++) {
      int s = 2 * w + i;
      int kt = s >> 2, ds2 = s & 3;
      gload_lds16(Kbh + (size_t)(T * 64 + kt * 32 + lq) * 64 + ds2 * 16 + hi * 8,
                  (char*)Ks[BSEL] + s * 1024);
      int f = s >> 1, dh = s & 1;
      gload_lds16(Vbh + (size_t)(dh * 32 + lq) * 1024 + T * 64 + f * 16 + hi * 8,
                  (char*)Vs[BSEL] + s * 1024);
    }
  };

  STAGE(0, 0);

  // ---- fused Q head-RMSNorm + RoPE + scale (wave's 32 q-rows; overlaps staging)
  bf16x8 qf[4];
  {
    int pos = q0 + w * 32 + lq;
    const __bf16* qp = Qt + ((size_t)(b * 4096 + pos) << 10) + h * 64 + hi * 8;
    float xf[4][8];
    float ss = 0.f;
#pragma unroll
    for (int ds = 0; ds < 4; ds++) {
      bf16x8 xv = *(const bf16x8*)(qp + ds * 16);
#pragma unroll
      for (int j = 0; j < 8; j++) { float f = (float)xv[j]; xf[ds][j] = f; ss += f * f; }
    }
    float2 sw = swap32(ss);
    float rn = rsqrtf((sw.x + sw.y) * (1.0f / 64.0f) + 1e-6f);
#pragma unroll
    for (int ds = 0; ds < 4; ds++) {
      int d0 = ds * 16 + hi * 8;
      const float* wp = QHW + d0;
      const float* cp = QCOS + ((size_t)pos << 6) + d0;
      const float* sp = QSIN + ((size_t)pos << 6) + d0;
      float4 wa = *(const float4*)wp, wb = *(const float4*)(wp + 4);
      float4 ca = *(const float4*)cp, cb = *(const float4*)(cp + 4);
      float4 sa = *(const float4*)sp, sb = *(const float4*)(sp + 4);
      float wv[8] = {wa.x, wa.y, wa.z, wa.w, wb.x, wb.y, wb.z, wb.w};
      float cv[8] = {ca.x, ca.y, ca.z, ca.w, cb.x, cb.y, cb.z, cb.w};
      float sv[8] = {sa.x, sa.y, sa.z, sa.w, sb.x, sb.y, sb.z, sb.w};
      float xn[8];
#pragma unroll
      for (int j = 0; j < 8; j++) xn[j] = xf[ds][j] * rn * wv[j];
      bf16x8 q8;
#pragma unroll
      for (int j = 0; j < 8; j += 2) {
        q8[j]     = (__bf16)((xn[j] * cv[j] - xn[j + 1] * sv[j]) * QSC);
        q8[j + 1] = (__bf16)((xn[j + 1] * cv[j + 1] + xn[j] * sv[j + 1]) * QSC);
      }
      qf[ds] = q8;
    }
  }

  f32x16 Z16;
#pragma unroll
  for (int r = 0; r < 16; r++) Z16[r] = 0.f;
  f32x16 accO[2];
  accO[0] = Z16; accO[1] = Z16;
  float srun = 0.f;

  int buf = 0;
  for (int t = 0; t < 16; t++) {
    if (t < 15) {
      STAGE(t + 1, buf ^ 1);
      asm volatile("s_waitcnt vmcnt(4)" ::: "memory");
    } else {
      asm volatile("s_waitcnt vmcnt(0)" ::: "memory");
    }
    __builtin_amdgcn_s_barrier();
    asm volatile("" ::: "memory");

    const char* kbase = (const char*)Ks[buf];
    const char* vbase = (const char*)Vs[buf];
    int loff = lane * 16;

    bf16x8 kf[8];
#pragma unroll
    for (int s = 0; s < 8; s++) kf[s] = *(const bf16x8*)(kbase + s * 1024 + loff);

    // S^T = K Q^T (first MFMA consumes Z16)
    f32x16 accS[2];
    __builtin_amdgcn_s_setprio(1);
#pragma unroll
    for (int kt = 0; kt < 2; kt++) {
      accS[kt] = __builtin_amdgcn_mfma_f32_32x32x16_bf16(kf[kt * 4], qf[0], Z16, 0, 0, 0);
#pragma unroll
      for (int ds = 1; ds < 4; ds++)
        accS[kt] = __builtin_amdgcn_mfma_f32_32x32x16_bf16(kf[kt * 4 + ds], qf[ds], accS[kt], 0, 0, 0);
    }
    __builtin_amdgcn_s_setprio(0);

    // P = exp2(S), row-sum, pack to A-frags (permlane32_swap half-exchange)
    float ssum = 0.f;
#pragma unroll
    for (int kt = 0; kt < 2; kt++)
#pragma unroll
      for (int r = 0; r < 16; r++) {
        float e = fast_exp2(accS[kt][r]);
        accS[kt][r] = e;
        ssum += e;
      }
    float2 sws = swap32(ssum);
    srun += sws.x + sws.y;

    unsigned pa[4][4];
#pragma unroll
    for (int kt = 0; kt < 2; kt++)
#pragma unroll
      for (int s2 = 0; s2 < 2; s2++) {
        int f = kt * 2 + s2, rb = s2 * 8;
        unsigned u  = pkbf(accS[kt][rb + 0], accS[kt][rb + 1]);
        unsigned v2 = pkbf(accS[kt][rb + 2], accS[kt][rb + 3]);
        unsigned w2 = pkbf(accS[kt][rb + 4], accS[kt][rb + 5]);
        unsigned x2 = pkbf(accS[kt][rb + 6], accS[kt][rb + 7]);
        u32x2 r02 = __builtin_amdgcn_permlane32_swap(u, w2, false, false);
        u32x2 r13 = __builtin_amdgcn_permlane32_swap(v2, x2, false, false);
        pa[f][0] = r02.x; pa[f][1] = r13.x; pa[f][2] = r02.y; pa[f][3] = r13.y;
      }

    bf16x8 vf[8];
#pragma unroll
    for (int s = 0; s < 8; s++) vf[s] = *(const bf16x8*)(vbase + s * 1024 + loff);

    __builtin_amdgcn_s_setprio(1);
#pragma unroll
    for (int f = 0; f < 4; f++) {
      union { unsigned u[4]; bf16x8 v; } pf;
      pf.u[0] = pa[f][0]; pf.u[1] = pa[f][1]; pf.u[2] = pa[f][2]; pf.u[3] = pa[f][3];
#pragma unroll
      for (int dh = 0; dh < 2; dh++)
        accO[dh] = __builtin_amdgcn_mfma_f32_32x32x16_bf16(pf.v, vf[f * 2 + dh], accO[dh], 0, 0, 0);
    }
    __builtin_amdgcn_s_setprio(0);

    __builtin_amdgcn_s_barrier();
    asm volatile("" ::: "memory");
    buf ^= 1;
  }

  // epilogue: per-q 1/sum via bpermute (q row cr lives in lane cr), bf16 stores
  __bf16* aobase = AO + (((size_t)b * 4096) << 10) + h * 64;
  float rinv = 1.0f / srun;
  int ri = __float_as_int(rinv);
#pragma unroll
  for (int r = 0; r < 16; r++) {
    int cr = (r & 3) + ((r >> 2) << 3) + (hi << 2);
    float rv = __int_as_float(__builtin_amdgcn_ds_bpermute(cr << 2, ri));
    size_t rowoff = ((size_t)(q0 + w * 32 + cr) << 10);
#pragma unroll
    for (int dh = 0; dh < 2; dh++)
      aobase[rowoff + dh * 32 + lq] = (__bf16)(accO[dh][r] * rv);
  }
}

extern "C" void kernel_launch(void* const* d_in, const int* in_sizes, int n_in,
                              void* d_out, int out_size, void* d_ws, size_t ws_size,
                              hipStream_t stream) {
  const float* img  = (const float*)d_in[0];
  const float* cnd  = (const float*)d_in[1];
  const float* qnw  = (const float*)d_in[2];
  const float* kvnw = (const float*)d_in[3];
  const float* qhw  = (const float*)d_in[4];
  const float* khw  = (const float*)d_in[5];
  const float* qw   = (const float*)d_in[6];
  const float* qb   = (const float*)d_in[7];
  const float* kw   = (const float*)d_in[8];
  const float* kb   = (const float*)d_in[9];
  const float* vw   = (const float*)d_in[10];
  const float* vb   = (const float*)d_in[11];
  const float* ow   = (const float*)d_in[12];
  const float* ob   = (const float*)d_in[13];
  const float* alpha= (const float*)d_in[14];
  const float* icos = (const float*)d_in[15];
  const float* isin = (const float*)d_in[16];
  const float* ccos = (const float*)d_in[17];
  const float* csin = (const float*)d_in[18];
  float* out = (float*)d_out;

  __bf16* p = (__bf16*)d_ws;
  __bf16* wqb = p; p += 1048576;
  __bf16* wkb = p; p += 1048576;   // wkb..wvb contiguous = (2048,1024) KV weight
  __bf16* wvb = p; p += 1048576;
  __bf16* wob = p; p += 1048576;
  __bf16* qn  = p; p += 8388608;   // (8192,1024); reused as AO after Q-GEMM consumes it
  __bf16* kvn = p; p += 2097152;
  __bf16* Qt  = p; p += 8388608;
  __bf16* Kt  = p; p += 2097152;
  __bf16* Vt0 = p; p += 2097152;
  __bf16* Kr  = p; p += 2097152;
  __bf16* Vtr = p; p += 2097152;
  __bf16* AO  = qn;  // qn dead after Q-GEMM

  prep_kernel<<<12288, 256, 0, stream>>>(img, qnw, qn, cnd, kvnw, kvn,
                                         qw, kw, vw, ow, wqb, wkb, wvb, wob);

  qkv_gemm_kernel<<<768, 256, 0, stream>>>(qn, kvn, wqb, wkb, qb, kb, vb, Qt, Kt, Vt0);

  kprep_kernel<<<1536, 256, 0, stream>>>(Kt, khw, ccos, csin, Kr, Vt0, Vtr);

  attn_kernel<<<1024, 256, 0, stream>>>(Qt, qhw, icos, isin, Kr, Vtr, AO);

  gemm_o_kernel<<<dim3(64, 8), 256, 0, stream>>>(AO, wob, ob, out, img, alpha);
}